// Round 1
// baseline (401.154 us; speedup 1.0000x reference)
//
#include <hip/hip_runtime.h>
#include <stdint.h>

// PinConv pipeline, round 11:
//  - B matrices (Q_w, W_w) pre-converted to bf16 ONCE in k_pre (was: f32->bf16
//    conversion of the whole B tile inside every GEMM block = ~4x the MFMA time).
//  - GEMM rewritten LDS-free: A and B MFMA fragments loaded directly from
//    global bf16 (A window fits L1, B is L2-hot). No K-loop barriers.
//  - Dispatch count 9 -> 6: k_coffs scan folded into last hist block of k_pre;
//    bn_coef folded into last GEMM block (done-counter + threadfence +
//    agent-scope atomic loads to dodge cross-XCD L2 staleness).

#define BN_EPS 1e-5f
#define NSLOT 32

typedef __attribute__((ext_vector_type(8))) short bf16x8;
typedef __attribute__((ext_vector_type(4))) float f32x4;

static __device__ __forceinline__ unsigned short f2bf(float f) {
    uint32_t u = __builtin_bit_cast(uint32_t, f);
    u += 0x7fffu + ((u >> 16) & 1u);          // round-to-nearest-even
    return (unsigned short)(u >> 16);
}
static __device__ __forceinline__ float bf_lo(uint32_t u) {
    return __builtin_bit_cast(float, u << 16);
}
static __device__ __forceinline__ float bf_hi(uint32_t u) {
    return __builtin_bit_cast(float, u & 0xffff0000u);
}

static __device__ __forceinline__ void cast_blk(
    const float* __restrict__ src, unsigned short* __restrict__ dst,
    int n, int blk)
{
    int i = (blk * 256 + threadIdx.x) * 4;
    if (i + 3 < n) {
        float4 v = *(const float4*)(src + i);
        ushort4 o;
        o.x = f2bf(v.x); o.y = f2bf(v.y); o.z = f2bf(v.z); o.w = f2bf(v.w);
        *(ushort4*)(dst + i) = o;
    } else {
        for (int j = i; j < n; ++j) dst[j] = f2bf(src[j]);
    }
}

// ---------------------------------------------------------------------------
// Fused: blocks [0,CB) cast feat; [CB,CB+HB) coarse-histogram dst (last one
// also does the 128-bucket exclusive scan); [CB+HB,..) cast Q_w / W_w to bf16.
__global__ __launch_bounds__(256) void k_pre(
    const float* __restrict__ feat, unsigned short* __restrict__ featb, int nf,
    const int* __restrict__ dst, int* __restrict__ ccnt, int E, int CB, int HB,
    const float* __restrict__ Qw, unsigned short* __restrict__ Qwb,
    const float* __restrict__ Ww, unsigned short* __restrict__ Wwb,
    int* __restrict__ done, int* __restrict__ coffs, int* __restrict__ gcur,
    int* __restrict__ offs, int N)
{
    int b = (int)blockIdx.x;
    if (b < CB) { cast_blk(feat, featb, nf, b); return; }
    b -= CB;
    if (b >= HB) {
        b -= HB;
        if (b < 16) cast_blk(Qw, Qwb, 128 * 128, b);
        else        cast_blk(Ww, Wwb, 128 * 256, b - 16);
        return;
    }
    // histogram bucket counts
    __shared__ int hcnt[128];
    __shared__ bool last;
    const int tid = threadIdx.x;
    if (tid < 128) hcnt[tid] = 0;
    __syncthreads();
    const int base_e = b * 2048;
#pragma unroll
    for (int j = 0; j < 8; ++j) {
        int e = base_e + j * 256 + tid;
        if (e < E) atomicAdd(&hcnt[dst[e] >> 9], 1);
    }
    __syncthreads();
    if (tid < 128 && hcnt[tid] > 0) atomicAdd(&ccnt[tid], hcnt[tid]);
    __threadfence();
    __syncthreads();
    if (tid == 0) last = (atomicAdd(&done[0], 1) == HB - 1);
    __syncthreads();
    if (!last) return;
    // last hist block: exclusive scan ccnt -> coffs[129], gcur, offs[N]=E
    __threadfence();
    __shared__ int w0sum;
    int v = 0, incl = 0;
    if (tid < 128) {
        v = __hip_atomic_load(&ccnt[tid], __ATOMIC_RELAXED, __HIP_MEMORY_SCOPE_AGENT);
        incl = v;
        const int lane = tid & 63;
#pragma unroll
        for (int o = 1; o < 64; o <<= 1) {
            int u = __shfl_up(incl, o, 64);
            if (lane >= o) incl += u;
        }
        if (tid == 63) w0sum = incl;
    }
    __syncthreads();
    if (tid < 128) {
        int excl = incl - v + ((tid >> 6) ? w0sum : 0);
        coffs[tid] = excl;
        gcur[tid]  = excl;
        if (tid == 127) { coffs[128] = excl + v; offs[N] = E; }
    }
}

// ---------------------------------------------------------------------------
// GEMM body, LDS-free: Y = relu(A @ B^T + bias). A rows bf16 from A_lo/A_hi
// (K split at 128), B bf16 [128][K]. Fragments loaded straight from global.
// Col sum/sumsq -> striped fp64 slots; LAST block reduces slots -> bn coefs.
template<int K>
static __device__ __forceinline__ void gemm_body(
    int bid,
    const unsigned short* __restrict__ A_lo,
    const unsigned short* __restrict__ A_hi,
    const unsigned short* __restrict__ Bb,
    const float* __restrict__ bias,
    float* __restrict__ Y,
    double* __restrict__ sum, double* __restrict__ sumsq, int N,
    int* __restrict__ done, int nblk,
    const float* __restrict__ gamma, const float* __restrict__ beta,
    float* __restrict__ a, float* __restrict__ b, double invN)
{
    __shared__ float bsum_s[128], bsq_s[128];
    __shared__ bool lastblk;

    const int tid  = threadIdx.x;
    const int lane = tid & 63;
    const int wv   = tid >> 6;
    const int wr   = wv >> 1;
    const int wc   = wv & 1;
    const int m15  = lane & 15;
    const int quad = lane >> 4;
    const int r0   = bid * 64;

    if (tid < 128) { bsum_s[tid] = 0.f; bsq_s[tid] = 0.f; }

    int ra0 = r0 + wr * 32 + m15;      if (ra0 >= N) ra0 = N - 1;
    int ra1 = r0 + wr * 32 + 16 + m15; if (ra1 >= N) ra1 = N - 1;
    const unsigned short* br0 = Bb + (size_t)(wc * 64 +  0 + m15) * K;
    const unsigned short* br1 = Bb + (size_t)(wc * 64 + 16 + m15) * K;
    const unsigned short* br2 = Bb + (size_t)(wc * 64 + 32 + m15) * K;
    const unsigned short* br3 = Bb + (size_t)(wc * 64 + 48 + m15) * K;

    f32x4 acc[2][4];
#pragma unroll
    for (int rt = 0; rt < 2; ++rt)
#pragma unroll
        for (int ct = 0; ct < 4; ++ct)
            acc[rt][ct] = (f32x4){0.f, 0.f, 0.f, 0.f};

#pragma unroll
    for (int kc = 0; kc < K; kc += 32) {
        const unsigned short* Ap = (kc < 128) ? A_lo : A_hi;
        const int ko = (kc & 127) + quad * 8;
        const int kb = kc + quad * 8;
        bf16x8 af0 = *(const bf16x8*)(Ap + (size_t)ra0 * 128 + ko);
        bf16x8 af1 = *(const bf16x8*)(Ap + (size_t)ra1 * 128 + ko);
        bf16x8 b0  = *(const bf16x8*)(br0 + kb);
        bf16x8 b1  = *(const bf16x8*)(br1 + kb);
        bf16x8 b2  = *(const bf16x8*)(br2 + kb);
        bf16x8 b3  = *(const bf16x8*)(br3 + kb);
        acc[0][0] = __builtin_amdgcn_mfma_f32_16x16x32_bf16(af0, b0, acc[0][0], 0, 0, 0);
        acc[1][0] = __builtin_amdgcn_mfma_f32_16x16x32_bf16(af1, b0, acc[1][0], 0, 0, 0);
        acc[0][1] = __builtin_amdgcn_mfma_f32_16x16x32_bf16(af0, b1, acc[0][1], 0, 0, 0);
        acc[1][1] = __builtin_amdgcn_mfma_f32_16x16x32_bf16(af1, b1, acc[1][1], 0, 0, 0);
        acc[0][2] = __builtin_amdgcn_mfma_f32_16x16x32_bf16(af0, b2, acc[0][2], 0, 0, 0);
        acc[1][2] = __builtin_amdgcn_mfma_f32_16x16x32_bf16(af1, b2, acc[1][2], 0, 0, 0);
        acc[0][3] = __builtin_amdgcn_mfma_f32_16x16x32_bf16(af0, b3, acc[0][3], 0, 0, 0);
        acc[1][3] = __builtin_amdgcn_mfma_f32_16x16x32_bf16(af1, b3, acc[1][3], 0, 0, 0);
    }

    __syncthreads();   // bsum_s/bsq_s init visible before LDS atomics

#pragma unroll
    for (int ct = 0; ct < 4; ++ct) {
        int col = wc * 64 + ct * 16 + m15;
        float bz = bias[col];
        float s = 0.f, q = 0.f;
#pragma unroll
        for (int rt = 0; rt < 2; ++rt) {
#pragma unroll
            for (int reg = 0; reg < 4; ++reg) {
                int row = r0 + wr * 32 + rt * 16 + quad * 4 + reg;
                float vv = fmaxf(acc[rt][ct][reg] + bz, 0.f);
                if (row < N) {
                    Y[(size_t)row * 128 + col] = vv;
                } else {
                    vv = 0.f;
                }
                s += vv; q = fmaf(vv, vv, q);
            }
        }
        s += __shfl_xor(s, 16, 64); s += __shfl_xor(s, 32, 64);
        q += __shfl_xor(q, 16, 64); q += __shfl_xor(q, 32, 64);
        if (quad == 0) {
            atomicAdd(&bsum_s[col], s);
            atomicAdd(&bsq_s[col], q);
        }
    }
    __syncthreads();
    if (tid < 128) {
        const int slot = (bid & (NSLOT - 1)) * 128;
        atomicAdd(&sum[slot + tid],   (double)bsum_s[tid]);
        atomicAdd(&sumsq[slot + tid], (double)bsq_s[tid]);
    }
    __threadfence();
    __syncthreads();
    if (tid == 0) lastblk = (atomicAdd(done, 1) == nblk - 1);
    __syncthreads();
    if (lastblk && tid < 128) {
        double ms = 0.0, qs = 0.0;
#pragma unroll
        for (int s2 = 0; s2 < NSLOT; ++s2) {
            ms += __hip_atomic_load(&sum[s2 * 128 + tid],   __ATOMIC_RELAXED, __HIP_MEMORY_SCOPE_AGENT);
            qs += __hip_atomic_load(&sumsq[s2 * 128 + tid], __ATOMIC_RELAXED, __HIP_MEMORY_SCOPE_AGENT);
        }
        float mean = (float)(ms * invN);
        float var  = (float)(qs * invN) - mean * mean;
        float sc = rsqrtf(var + BN_EPS) * gamma[tid];
        a[tid] = sc;
        b[tid] = fmaf(-mean, sc, beta[tid]);
    }
}

// ---------------------------------------------------------------------------
// bin body: bin edges into coarse buckets of 512 dsts (int4 records).
static __device__ __forceinline__ void bin_body(
    int bid,
    const int* __restrict__ src, const int* __restrict__ dst,
    const float* __restrict__ w, int* __restrict__ gcur,
    int4* __restrict__ tmp, int E)
{
    __shared__ int hcnt[128];
    __shared__ int hbase[128];
    const int tid = threadIdx.x;
    if (tid < 128) hcnt[tid] = 0;
    __syncthreads();

    int d8[8], s8[8], slot8[8];
    float w8[8];
#pragma unroll
    for (int j = 0; j < 8; ++j) {
        int e = bid * 2048 + j * 256 + tid;
        if (e < E) {
            d8[j] = dst[e]; s8[j] = src[e]; w8[j] = w[e];
            slot8[j] = atomicAdd(&hcnt[d8[j] >> 9], 1);
        } else d8[j] = -1;
    }
    __syncthreads();
    if (tid < 128 && hcnt[tid] > 0)
        hbase[tid] = atomicAdd(&gcur[tid], hcnt[tid]);
    __syncthreads();
#pragma unroll
    for (int j = 0; j < 8; ++j) {
        if (d8[j] >= 0) {
            int pos = hbase[d8[j] >> 9] + slot8[j];
            tmp[pos] = make_int4(s8[j], __float_as_int(w8[j]), d8[j], 0);
        }
    }
}

// fatB: blocks [0,HB) bin edges; blocks [HB,HB+GB) run gemm1 (+bn coefs).
__global__ __launch_bounds__(256) void k_bin_gemm(
    const int* __restrict__ src, const int* __restrict__ dst,
    const float* __restrict__ w, int* __restrict__ gcur,
    int4* __restrict__ tmp, int E, int HB,
    const unsigned short* __restrict__ featb,
    const unsigned short* __restrict__ Qwb, const float* __restrict__ Qb,
    float* __restrict__ y1,
    double* __restrict__ sum, double* __restrict__ sumsq, int N,
    int* __restrict__ done, int GB,
    const float* __restrict__ gamma, const float* __restrict__ beta,
    float* __restrict__ a, float* __restrict__ b, double invN)
{
    if ((int)blockIdx.x < HB)
        bin_body(blockIdx.x, src, dst, w, gcur, tmp, E);
    else
        gemm_body<128>(blockIdx.x - HB, featb, featb, Qwb, Qb, y1, sum, sumsq, N,
                       done, GB, gamma, beta, a, b, invN);
}

// ---------------------------------------------------------------------------
// refine body: per bucket — count per-dst in LDS, scan (+coffs base), write
// offs slice, scatter records to epack in exact dst order.
static __device__ __forceinline__ void refine_body(
    int b,
    const int4* __restrict__ tmp, const int* __restrict__ coffs,
    int* __restrict__ offs, int2* __restrict__ epack, int N)
{
    __shared__ int hist[512];
    __shared__ int wpre[4];
    const int d0   = b << 9;
    const int dlim = min(512, N - d0);
    const int tid  = threadIdx.x;
    const int lane = tid & 63, wv = tid >> 6;
    const int start = coffs[b];
    const int end   = coffs[b + 1];

    hist[tid] = 0; hist[tid + 256] = 0;
    __syncthreads();

    for (int p = start + tid; p < end; p += 256)
        atomicAdd(&hist[tmp[p].z - d0], 1);
    __syncthreads();

    int v0 = hist[2 * tid], v1 = hist[2 * tid + 1];
    int s = v0 + v1;
    int incl = s;
#pragma unroll
    for (int o = 1; o < 64; o <<= 1) {
        int t = __shfl_up(incl, o, 64);
        if (lane >= o) incl += t;
    }
    if (lane == 63) wpre[wv] = incl;
    __syncthreads();
    if (tid == 0) {
        int r = 0;
#pragma unroll
        for (int i = 0; i < 4; ++i) { int t = wpre[i]; wpre[i] = r; r += t; }
    }
    __syncthreads();
    int e0 = start + wpre[wv] + incl - s;
    if (2 * tid < dlim)     offs[d0 + 2 * tid]     = e0;
    if (2 * tid + 1 < dlim) offs[d0 + 2 * tid + 1] = e0 + v0;
    hist[2 * tid]     = e0;
    hist[2 * tid + 1] = e0 + v0;
    __syncthreads();

    for (int p = start + tid; p < end; p += 256) {
        int4 rec = tmp[p];
        int pos = atomicAdd(&hist[rec.z - d0], 1);
        epack[pos] = make_int2(rec.x, rec.y);
    }
}

// fatC: blocks [0,NB) refine buckets; blocks [NB,..) apply bn -> h bf16.
__global__ __launch_bounds__(256) void k_refine_apply(
    const int4* __restrict__ tmp, const int* __restrict__ coffs,
    int* __restrict__ offs, int2* __restrict__ epack, int N, int NB,
    const float* __restrict__ y,
    const float* __restrict__ a, const float* __restrict__ b,
    unsigned short* __restrict__ h, int n)
{
    if ((int)blockIdx.x < NB) {
        refine_body(blockIdx.x, tmp, coffs, offs, epack, N);
    } else {
        int i = ((blockIdx.x - NB) * 256 + threadIdx.x) * 4;
        if (i >= n) return;
        int c = i & 127;
        float4 v  = *(const float4*)(y + i);
        float4 av = *(const float4*)(a + c);
        float4 bv = *(const float4*)(b + c);
        ushort4 o;
        o.x = f2bf(fmaf(av.x, v.x, bv.x));
        o.y = f2bf(fmaf(av.y, v.y, bv.y));
        o.z = f2bf(fmaf(av.z, v.z, bv.z));
        o.w = f2bf(fmaf(av.w, v.w, bv.w));
        *(ushort4*)(h + i) = o;
    }
}

// ---------------------------------------------------------------------------
// One wave per dst row; h bf16 (bn applied). Writes agg only (bf16).
__global__ __launch_bounds__(256) void gather_agg(
    const unsigned short* __restrict__ h,
    const int* __restrict__ offs, const int2* __restrict__ epack,
    unsigned short* __restrict__ aggb, int N)
{
    const int r    = (int)((blockIdx.x * 256u + threadIdx.x) >> 6);
    const int lane = threadIdx.x & 63;
    if (r >= N) return;
    int p = offs[r];
    const int end = offs[r + 1];
    float nx = 0.f, ny = 0.f, den = 0.f;
    for (; p + 3 < end; p += 4) {
        int2 e0 = epack[p],     e1 = epack[p + 1];
        int2 e2 = epack[p + 2], e3 = epack[p + 3];
        uint32_t u0 = *(const uint32_t*)(h + (size_t)e0.x * 128 + 2 * lane);
        uint32_t u1 = *(const uint32_t*)(h + (size_t)e1.x * 128 + 2 * lane);
        uint32_t u2 = *(const uint32_t*)(h + (size_t)e2.x * 128 + 2 * lane);
        uint32_t u3 = *(const uint32_t*)(h + (size_t)e3.x * 128 + 2 * lane);
        float w0 = __int_as_float(e0.y), w1 = __int_as_float(e1.y);
        float w2 = __int_as_float(e2.y), w3 = __int_as_float(e3.y);
        nx = fmaf(w0, bf_lo(u0), nx); ny = fmaf(w0, bf_hi(u0), ny);
        nx = fmaf(w1, bf_lo(u1), nx); ny = fmaf(w1, bf_hi(u1), ny);
        nx = fmaf(w2, bf_lo(u2), nx); ny = fmaf(w2, bf_hi(u2), ny);
        nx = fmaf(w3, bf_lo(u3), nx); ny = fmaf(w3, bf_hi(u3), ny);
        den += (w0 + w1) + (w2 + w3);
    }
    for (; p < end; ++p) {
        int2 e0 = epack[p];
        float w0 = __int_as_float(e0.y);
        uint32_t u0 = *(const uint32_t*)(h + (size_t)e0.x * 128 + 2 * lane);
        nx = fmaf(w0, bf_lo(u0), nx); ny = fmaf(w0, bf_hi(u0), ny);
        den += w0;
    }
    float2 outv;
    if (den != 0.f) {
        float inv = 1.f / den;
        outv.x = nx * inv; outv.y = ny * inv;
    } else {
        uint32_t u = *(const uint32_t*)(h + (size_t)r * 128 + 2 * lane);
        outv.x = bf_lo(u); outv.y = bf_hi(u);
    }
    ushort2 ao; ao.x = f2bf(outv.x); ao.y = f2bf(outv.y);
    *(ushort2*)&aggb[(size_t)r * 128 + 2 * lane] = ao;
}

// ---------------------------------------------------------------------------
// gemm2 standalone (K=256, A = [featb|aggb]) + bn2 coefs in last block.
__global__ __launch_bounds__(256) void gemm_bn2(
    const unsigned short* __restrict__ A_lo,
    const unsigned short* __restrict__ A_hi,
    const unsigned short* __restrict__ Bb,
    const float* __restrict__ bias,
    float* __restrict__ Y,
    double* __restrict__ sum, double* __restrict__ sumsq, int N,
    int* __restrict__ done, int GB,
    const float* __restrict__ gamma, const float* __restrict__ beta,
    float* __restrict__ a, float* __restrict__ b, double invN)
{
    gemm_body<256>(blockIdx.x, A_lo, A_hi, Bb, bias, Y, sum, sumsq, N,
                   done, GB, gamma, beta, a, b, invN);
}

// ---------------------------------------------------------------------------
// bn2 affine (precomputed coefs) + row L2 normalize.
__global__ __launch_bounds__(256) void finalize(
    const float* __restrict__ Y2,
    const float* __restrict__ a, const float* __restrict__ b,
    float* __restrict__ out, int N)
{
    __shared__ float sa[128], sb[128];
    const int t = threadIdx.x;
    if (t < 128) { sa[t] = a[t]; sb[t] = b[t]; }
    __syncthreads();
    const int row  = (int)((blockIdx.x * 256u + t) >> 6);
    const int lane = t & 63;
    if (row >= N) return;
    const size_t base = (size_t)row * 128;
    float v0 = fmaf(sa[lane],      Y2[base + lane],      sb[lane]);
    float v1 = fmaf(sa[lane + 64], Y2[base + lane + 64], sb[lane + 64]);
    float ss = fmaf(v0, v0, v1 * v1);
#pragma unroll
    for (int o = 32; o; o >>= 1) ss += __shfl_xor(ss, o, 64);
    float nrm = sqrtf(ss);
    float inv = (nrm == 0.f) ? 1.f : 1.f / nrm;
    out[base + lane]      = v0 * inv;
    out[base + lane + 64] = v1 * inv;
}

// ---------------------------------------------------------------------------
extern "C" void kernel_launch(void* const* d_in, const int* in_sizes, int n_in,
                              void* d_out, int out_size, void* d_ws, size_t ws_size,
                              hipStream_t stream)
{
    const float* feat   = (const float*)d_in[0];
    const float* w      = (const float*)d_in[1];
    const float* Q_w    = (const float*)d_in[2];
    const float* Q_b    = (const float*)d_in[3];
    const float* W_w    = (const float*)d_in[4];
    const float* W_b    = (const float*)d_in[5];
    const float* gamma2 = (const float*)d_in[6];
    const float* beta2  = (const float*)d_in[7];
    const int*   src    = (const int*)d_in[8];
    const int*   dst    = (const int*)d_in[9];

    const int N = in_sizes[0] / 128;   // 50000
    const int E = in_sizes[1];         // 800000

    // workspace layout
    float*          y1    = (float*)d_ws;                            // N*128 f32 (y1 then y2)
    unsigned short* featb = (unsigned short*)(y1 + (size_t)N * 128); // N*128 bf16
    unsigned short* aggb  = featb + (size_t)N * 128;                 // N*128 bf16
    unsigned short* h_bf  = aggb + (size_t)N * 128;                  // N*128 bf16
    int4*  tmp    = (int4*)(h_bf + (size_t)N * 128);                 // E (16B aligned)
    int2*  epack  = (int2*)(tmp + E);                                // E
    int*   offs   = (int*)(epack + E);                               // N+1
    int*   coffs  = offs + (N + 1);                                  // 129
    int*   gcur   = coffs + 129;                                     // 128
    float* coefs  = (float*)(gcur + 128);                            // 512
    float* a1 = coefs, *b1 = coefs + 128, *a2 = coefs + 256, *b2 = coefs + 384;
    uintptr_t qp = ((uintptr_t)(coefs + 512) + 15) & ~(uintptr_t)15;
    unsigned short* Qwb = (unsigned short*)qp;                       // 128*128 bf16
    unsigned short* Wwb = Qwb + 128 * 128;                           // 128*256 bf16
    uintptr_t sp = ((uintptr_t)(Wwb + 128 * 256) + 15) & ~(uintptr_t)15;
    double* stats = (double*)sp;                                     // 4*NSLOT*128 <- zeroed
    double* sum1   = stats;
    double* sumsq1 = stats + NSLOT * 128;
    double* sum2   = stats + 2 * NSLOT * 128;
    double* sumsq2 = stats + 3 * NSLOT * 128;
    int*   ccnt   = (int*)(stats + 4 * NSLOT * 128);                 // 128 <- zeroed
    int*   done   = ccnt + 128;                                      // 4   <- zeroed

    hipMemsetAsync(stats, 0,
                   4 * NSLOT * 128 * sizeof(double) + 132 * sizeof(int),
                   stream);

    const double invN = 1.0 / (double)N;
    const int GB = (N + 63) / 64;               // gemm blocks (782)
    const int NB = (N + 511) >> 9;              // coarse buckets (98)
    const int CB = (N * 128 / 4 + 255) / 256;   // feat cast blocks
    const int HB = (E + 2047) / 2048;           // histogram/bin blocks
    const int AB = (N * 128 / 4 + 255) / 256;   // apply_bn blocks
    const int QB = 16;                          // Q_w cast blocks (16384/1024)
    const int WB = 32;                          // W_w cast blocks (32768/1024)

    k_pre<<<CB + HB + QB + WB, 256, 0, stream>>>(
        feat, featb, N * 128, dst, ccnt, E, CB, HB,
        Q_w, Qwb, W_w, Wwb, done, coffs, gcur, offs, N);

    // fatB: bin || gemm1 (+bn1 coefs in last gemm block)
    k_bin_gemm<<<HB + GB, 256, 0, stream>>>(
        src, dst, w, gcur, tmp, E, HB,
        featb, Qwb, Q_b, y1, sum1, sumsq1, N,
        done + 1, GB, gamma2, beta2, a1, b1, invN);

    // fatC: refine || apply_bn
    k_refine_apply<<<NB + AB, 256, 0, stream>>>(
        tmp, coffs, offs, epack, N, NB,
        y1, a1, b1, h_bf, N * 128);

    gather_agg<<<(N * 64 + 255) / 256, 256, 0, stream>>>(h_bf, offs, epack, aggb, N);

    gemm_bn2<<<GB, 256, 0, stream>>>(
        featb, aggb, Wwb, W_b, y1 /*=y2*/, sum2, sumsq2, N,
        done + 2, GB, gamma2, beta2, a2, b2, invN);

    finalize<<<(N * 64 + 255) / 256, 256, 0, stream>>>(
        y1, a2, b2, (float*)d_out, N);
}

// Round 2
// 387.713 us; speedup vs baseline: 1.0347x; 1.0347x over previous
//
#include <hip/hip_runtime.h>
#include <stdint.h>

// PinConv pipeline, round 12:
//  - REVERT the LDS-free GEMM (round 11 regression: latency-bound scattered
//    fragment loads, MfmaUtil 0.5%). Back to LDS-staged tiles (coalesced
//    128B row-segment loads, SA=72 padding).
//  - KEEP from round 11: B matrices pre-converted to bf16 once in k_pre
//    (B staging is now pure uint4 copy, no f2bf VALU in the K-loop), and
//    the dispatch fusion (6 dispatches: coffs-scan folded into k_pre,
//    bn_coef folded into last GEMM block via done-counter + threadfence +
//    agent-scope atomic loads).

#define BN_EPS 1e-5f
#define NSLOT 32

typedef __attribute__((ext_vector_type(8))) short bf16x8;
typedef __attribute__((ext_vector_type(4))) float f32x4;

static __device__ __forceinline__ unsigned short f2bf(float f) {
    uint32_t u = __builtin_bit_cast(uint32_t, f);
    u += 0x7fffu + ((u >> 16) & 1u);          // round-to-nearest-even
    return (unsigned short)(u >> 16);
}
static __device__ __forceinline__ float bf_lo(uint32_t u) {
    return __builtin_bit_cast(float, u << 16);
}
static __device__ __forceinline__ float bf_hi(uint32_t u) {
    return __builtin_bit_cast(float, u & 0xffff0000u);
}

static __device__ __forceinline__ void cast_blk(
    const float* __restrict__ src, unsigned short* __restrict__ dst,
    int n, int blk)
{
    int i = (blk * 256 + threadIdx.x) * 4;
    if (i + 3 < n) {
        float4 v = *(const float4*)(src + i);
        ushort4 o;
        o.x = f2bf(v.x); o.y = f2bf(v.y); o.z = f2bf(v.z); o.w = f2bf(v.w);
        *(ushort4*)(dst + i) = o;
    } else {
        for (int j = i; j < n; ++j) dst[j] = f2bf(src[j]);
    }
}

// ---------------------------------------------------------------------------
// Fused: blocks [0,CB) cast feat; [CB,CB+HB) coarse-histogram dst (last one
// also does the 128-bucket exclusive scan); [CB+HB,..) cast Q_w / W_w to bf16.
__global__ __launch_bounds__(256) void k_pre(
    const float* __restrict__ feat, unsigned short* __restrict__ featb, int nf,
    const int* __restrict__ dst, int* __restrict__ ccnt, int E, int CB, int HB,
    const float* __restrict__ Qw, unsigned short* __restrict__ Qwb,
    const float* __restrict__ Ww, unsigned short* __restrict__ Wwb,
    int* __restrict__ done, int* __restrict__ coffs, int* __restrict__ gcur,
    int* __restrict__ offs, int N)
{
    int b = (int)blockIdx.x;
    if (b < CB) { cast_blk(feat, featb, nf, b); return; }
    b -= CB;
    if (b >= HB) {
        b -= HB;
        if (b < 16) cast_blk(Qw, Qwb, 128 * 128, b);
        else        cast_blk(Ww, Wwb, 128 * 256, b - 16);
        return;
    }
    // histogram bucket counts
    __shared__ int hcnt[128];
    __shared__ bool last;
    const int tid = threadIdx.x;
    if (tid < 128) hcnt[tid] = 0;
    __syncthreads();
    const int base_e = b * 2048;
#pragma unroll
    for (int j = 0; j < 8; ++j) {
        int e = base_e + j * 256 + tid;
        if (e < E) atomicAdd(&hcnt[dst[e] >> 9], 1);
    }
    __syncthreads();
    if (tid < 128 && hcnt[tid] > 0) atomicAdd(&ccnt[tid], hcnt[tid]);
    __threadfence();
    __syncthreads();
    if (tid == 0) last = (atomicAdd(&done[0], 1) == HB - 1);
    __syncthreads();
    if (!last) return;
    // last hist block: exclusive scan ccnt -> coffs[129], gcur, offs[N]=E
    __threadfence();
    __shared__ int w0sum;
    int v = 0, incl = 0;
    if (tid < 128) {
        v = __hip_atomic_load(&ccnt[tid], __ATOMIC_RELAXED, __HIP_MEMORY_SCOPE_AGENT);
        incl = v;
        const int lane = tid & 63;
#pragma unroll
        for (int o = 1; o < 64; o <<= 1) {
            int u = __shfl_up(incl, o, 64);
            if (lane >= o) incl += u;
        }
        if (tid == 63) w0sum = incl;
    }
    __syncthreads();
    if (tid < 128) {
        int excl = incl - v + ((tid >> 6) ? w0sum : 0);
        coffs[tid] = excl;
        gcur[tid]  = excl;
        if (tid == 127) { coffs[128] = excl + v; offs[N] = E; }
    }
}

// ---------------------------------------------------------------------------
// GEMM body (LDS-staged): Y = relu(A @ B^T + bias). A rows from A_lo/A_hi
// (K split at 128), bf16. B bf16 [128][K] (pre-converted). Col sum/sumsq ->
// striped fp64 slots; LAST block reduces slots -> bn affine coefs.
template<int K>
static __device__ __forceinline__ void gemm_body(
    int bid,
    const unsigned short* __restrict__ A_lo,
    const unsigned short* __restrict__ A_hi,
    const unsigned short* __restrict__ Bb,
    const float* __restrict__ bias,
    float* __restrict__ Y,
    double* __restrict__ sum, double* __restrict__ sumsq, int N,
    int* __restrict__ done, int nblk,
    const float* __restrict__ gamma, const float* __restrict__ beta,
    float* __restrict__ a, float* __restrict__ b, double invN)
{
    constexpr int SA = 72;
    __shared__ unsigned short As[64 * SA];
    __shared__ unsigned short Bs[128 * SA];
    __shared__ float bsum_s[128], bsq_s[128];
    __shared__ bool lastblk;

    const int tid  = threadIdx.x;
    const int lane = tid & 63;
    const int wv   = tid >> 6;
    const int wr   = wv >> 1;
    const int wc   = wv & 1;
    const int m15  = lane & 15;
    const int quad = lane >> 4;
    const int r0   = bid * 64;

    if (tid < 128) { bsum_s[tid] = 0.f; bsq_s[tid] = 0.f; }

    f32x4 acc[2][4];
#pragma unroll
    for (int rt = 0; rt < 2; ++rt)
#pragma unroll
        for (int ct = 0; ct < 4; ++ct)
            acc[rt][ct] = (f32x4){0.f, 0.f, 0.f, 0.f};

    for (int kc = 0; kc < K; kc += 64) {
        const unsigned short* Ap = (kc < 128) ? A_lo : A_hi;
        const int koff = kc & 127;
        // A tile: 64 rows x 64 bf16 = 8 KB -> 2 x 256 x 16B
#pragma unroll
        for (int i = 0; i < 2; ++i) {
            int idx = i * 256 + tid;
            int row = idx >> 3, seg = idx & 7;
            int gr  = r0 + row; if (gr >= N) gr = N - 1;
            uint4 v = *(const uint4*)(Ap + (size_t)gr * 128 + koff + seg * 8);
            *(uint4*)(As + row * SA + seg * 8) = v;
        }
        // B tile: 128 rows x 64 bf16 = 16 KB -> 4 x 256 x 16B (pure copy)
#pragma unroll
        for (int i = 0; i < 4; ++i) {
            int idx = i * 256 + tid;
            int row = idx >> 3, seg = idx & 7;
            uint4 v = *(const uint4*)(Bb + (size_t)row * K + kc + seg * 8);
            *(uint4*)(Bs + row * SA + seg * 8) = v;
        }
        __syncthreads();

#pragma unroll
        for (int ks = 0; ks < 64; ks += 32) {
            bf16x8 af[2], bfr[4];
#pragma unroll
            for (int rt = 0; rt < 2; ++rt)
                af[rt] = *(const bf16x8*)(As + (wr * 32 + rt * 16 + m15) * SA + ks + quad * 8);
#pragma unroll
            for (int ct = 0; ct < 4; ++ct)
                bfr[ct] = *(const bf16x8*)(Bs + (wc * 64 + ct * 16 + m15) * SA + ks + quad * 8);
#pragma unroll
            for (int rt = 0; rt < 2; ++rt)
#pragma unroll
                for (int ct = 0; ct < 4; ++ct)
                    acc[rt][ct] = __builtin_amdgcn_mfma_f32_16x16x32_bf16(
                        af[rt], bfr[ct], acc[rt][ct], 0, 0, 0);
        }
        __syncthreads();
    }

#pragma unroll
    for (int ct = 0; ct < 4; ++ct) {
        int col = wc * 64 + ct * 16 + m15;
        float bz = bias[col];
        float s = 0.f, q = 0.f;
#pragma unroll
        for (int rt = 0; rt < 2; ++rt) {
#pragma unroll
            for (int reg = 0; reg < 4; ++reg) {
                int row = r0 + wr * 32 + rt * 16 + quad * 4 + reg;
                float vv = fmaxf(acc[rt][ct][reg] + bz, 0.f);
                if (row < N) {
                    Y[(size_t)row * 128 + col] = vv;
                } else {
                    vv = 0.f;
                }
                s += vv; q = fmaf(vv, vv, q);
            }
        }
        s += __shfl_xor(s, 16, 64); s += __shfl_xor(s, 32, 64);
        q += __shfl_xor(q, 16, 64); q += __shfl_xor(q, 32, 64);
        if (quad == 0) {
            atomicAdd(&bsum_s[col], s);
            atomicAdd(&bsq_s[col], q);
        }
    }
    __syncthreads();
    if (tid < 128) {
        const int slot = (bid & (NSLOT - 1)) * 128;
        atomicAdd(&sum[slot + tid],   (double)bsum_s[tid]);
        atomicAdd(&sumsq[slot + tid], (double)bsq_s[tid]);
    }
    __threadfence();
    __syncthreads();
    if (tid == 0) lastblk = (atomicAdd(done, 1) == nblk - 1);
    __syncthreads();
    if (lastblk && tid < 128) {
        double ms = 0.0, qs = 0.0;
#pragma unroll
        for (int s2 = 0; s2 < NSLOT; ++s2) {
            ms += __hip_atomic_load(&sum[s2 * 128 + tid],   __ATOMIC_RELAXED, __HIP_MEMORY_SCOPE_AGENT);
            qs += __hip_atomic_load(&sumsq[s2 * 128 + tid], __ATOMIC_RELAXED, __HIP_MEMORY_SCOPE_AGENT);
        }
        float mean = (float)(ms * invN);
        float var  = (float)(qs * invN) - mean * mean;
        float sc = rsqrtf(var + BN_EPS) * gamma[tid];
        a[tid] = sc;
        b[tid] = fmaf(-mean, sc, beta[tid]);
    }
}

// ---------------------------------------------------------------------------
// bin body: bin edges into coarse buckets of 512 dsts (int4 records).
static __device__ __forceinline__ void bin_body(
    int bid,
    const int* __restrict__ src, const int* __restrict__ dst,
    const float* __restrict__ w, int* __restrict__ gcur,
    int4* __restrict__ tmp, int E)
{
    __shared__ int hcnt[128];
    __shared__ int hbase[128];
    const int tid = threadIdx.x;
    if (tid < 128) hcnt[tid] = 0;
    __syncthreads();

    int d8[8], s8[8], slot8[8];
    float w8[8];
#pragma unroll
    for (int j = 0; j < 8; ++j) {
        int e = bid * 2048 + j * 256 + tid;
        if (e < E) {
            d8[j] = dst[e]; s8[j] = src[e]; w8[j] = w[e];
            slot8[j] = atomicAdd(&hcnt[d8[j] >> 9], 1);
        } else d8[j] = -1;
    }
    __syncthreads();
    if (tid < 128 && hcnt[tid] > 0)
        hbase[tid] = atomicAdd(&gcur[tid], hcnt[tid]);
    __syncthreads();
#pragma unroll
    for (int j = 0; j < 8; ++j) {
        if (d8[j] >= 0) {
            int pos = hbase[d8[j] >> 9] + slot8[j];
            tmp[pos] = make_int4(s8[j], __float_as_int(w8[j]), d8[j], 0);
        }
    }
}

// fatB: blocks [0,HB) bin edges; blocks [HB,HB+GB) run gemm1 (+bn coefs).
__global__ __launch_bounds__(256) void k_bin_gemm(
    const int* __restrict__ src, const int* __restrict__ dst,
    const float* __restrict__ w, int* __restrict__ gcur,
    int4* __restrict__ tmp, int E, int HB,
    const unsigned short* __restrict__ featb,
    const unsigned short* __restrict__ Qwb, const float* __restrict__ Qb,
    float* __restrict__ y1,
    double* __restrict__ sum, double* __restrict__ sumsq, int N,
    int* __restrict__ done, int GB,
    const float* __restrict__ gamma, const float* __restrict__ beta,
    float* __restrict__ a, float* __restrict__ b, double invN)
{
    if ((int)blockIdx.x < HB)
        bin_body(blockIdx.x, src, dst, w, gcur, tmp, E);
    else
        gemm_body<128>(blockIdx.x - HB, featb, featb, Qwb, Qb, y1, sum, sumsq, N,
                       done, GB, gamma, beta, a, b, invN);
}

// ---------------------------------------------------------------------------
// refine body: per bucket — count per-dst in LDS, scan (+coffs base), write
// offs slice, scatter records to epack in exact dst order.
static __device__ __forceinline__ void refine_body(
    int b,
    const int4* __restrict__ tmp, const int* __restrict__ coffs,
    int* __restrict__ offs, int2* __restrict__ epack, int N)
{
    __shared__ int hist[512];
    __shared__ int wpre[4];
    const int d0   = b << 9;
    const int dlim = min(512, N - d0);
    const int tid  = threadIdx.x;
    const int lane = tid & 63, wv = tid >> 6;
    const int start = coffs[b];
    const int end   = coffs[b + 1];

    hist[tid] = 0; hist[tid + 256] = 0;
    __syncthreads();

    for (int p = start + tid; p < end; p += 256)
        atomicAdd(&hist[tmp[p].z - d0], 1);
    __syncthreads();

    int v0 = hist[2 * tid], v1 = hist[2 * tid + 1];
    int s = v0 + v1;
    int incl = s;
#pragma unroll
    for (int o = 1; o < 64; o <<= 1) {
        int t = __shfl_up(incl, o, 64);
        if (lane >= o) incl += t;
    }
    if (lane == 63) wpre[wv] = incl;
    __syncthreads();
    if (tid == 0) {
        int r = 0;
#pragma unroll
        for (int i = 0; i < 4; ++i) { int t = wpre[i]; wpre[i] = r; r += t; }
    }
    __syncthreads();
    int e0 = start + wpre[wv] + incl - s;
    if (2 * tid < dlim)     offs[d0 + 2 * tid]     = e0;
    if (2 * tid + 1 < dlim) offs[d0 + 2 * tid + 1] = e0 + v0;
    hist[2 * tid]     = e0;
    hist[2 * tid + 1] = e0 + v0;
    __syncthreads();

    for (int p = start + tid; p < end; p += 256) {
        int4 rec = tmp[p];
        int pos = atomicAdd(&hist[rec.z - d0], 1);
        epack[pos] = make_int2(rec.x, rec.y);
    }
}

// fatC: blocks [0,NB) refine buckets; blocks [NB,..) apply bn -> h bf16.
__global__ __launch_bounds__(256) void k_refine_apply(
    const int4* __restrict__ tmp, const int* __restrict__ coffs,
    int* __restrict__ offs, int2* __restrict__ epack, int N, int NB,
    const float* __restrict__ y,
    const float* __restrict__ a, const float* __restrict__ b,
    unsigned short* __restrict__ h, int n)
{
    if ((int)blockIdx.x < NB) {
        refine_body(blockIdx.x, tmp, coffs, offs, epack, N);
    } else {
        int i = ((blockIdx.x - NB) * 256 + threadIdx.x) * 4;
        if (i >= n) return;
        int c = i & 127;
        float4 v  = *(const float4*)(y + i);
        float4 av = *(const float4*)(a + c);
        float4 bv = *(const float4*)(b + c);
        ushort4 o;
        o.x = f2bf(fmaf(av.x, v.x, bv.x));
        o.y = f2bf(fmaf(av.y, v.y, bv.y));
        o.z = f2bf(fmaf(av.z, v.z, bv.z));
        o.w = f2bf(fmaf(av.w, v.w, bv.w));
        *(ushort4*)(h + i) = o;
    }
}

// ---------------------------------------------------------------------------
// One wave per dst row; h bf16 (bn applied). Writes agg only (bf16).
__global__ __launch_bounds__(256) void gather_agg(
    const unsigned short* __restrict__ h,
    const int* __restrict__ offs, const int2* __restrict__ epack,
    unsigned short* __restrict__ aggb, int N)
{
    const int r    = (int)((blockIdx.x * 256u + threadIdx.x) >> 6);
    const int lane = threadIdx.x & 63;
    if (r >= N) return;
    int p = offs[r];
    const int end = offs[r + 1];
    float nx = 0.f, ny = 0.f, den = 0.f;
    for (; p + 3 < end; p += 4) {
        int2 e0 = epack[p],     e1 = epack[p + 1];
        int2 e2 = epack[p + 2], e3 = epack[p + 3];
        uint32_t u0 = *(const uint32_t*)(h + (size_t)e0.x * 128 + 2 * lane);
        uint32_t u1 = *(const uint32_t*)(h + (size_t)e1.x * 128 + 2 * lane);
        uint32_t u2 = *(const uint32_t*)(h + (size_t)e2.x * 128 + 2 * lane);
        uint32_t u3 = *(const uint32_t*)(h + (size_t)e3.x * 128 + 2 * lane);
        float w0 = __int_as_float(e0.y), w1 = __int_as_float(e1.y);
        float w2 = __int_as_float(e2.y), w3 = __int_as_float(e3.y);
        nx = fmaf(w0, bf_lo(u0), nx); ny = fmaf(w0, bf_hi(u0), ny);
        nx = fmaf(w1, bf_lo(u1), nx); ny = fmaf(w1, bf_hi(u1), ny);
        nx = fmaf(w2, bf_lo(u2), nx); ny = fmaf(w2, bf_hi(u2), ny);
        nx = fmaf(w3, bf_lo(u3), nx); ny = fmaf(w3, bf_hi(u3), ny);
        den += (w0 + w1) + (w2 + w3);
    }
    for (; p < end; ++p) {
        int2 e0 = epack[p];
        float w0 = __int_as_float(e0.y);
        uint32_t u0 = *(const uint32_t*)(h + (size_t)e0.x * 128 + 2 * lane);
        nx = fmaf(w0, bf_lo(u0), nx); ny = fmaf(w0, bf_hi(u0), ny);
        den += w0;
    }
    float2 outv;
    if (den != 0.f) {
        float inv = 1.f / den;
        outv.x = nx * inv; outv.y = ny * inv;
    } else {
        uint32_t u = *(const uint32_t*)(h + (size_t)r * 128 + 2 * lane);
        outv.x = bf_lo(u); outv.y = bf_hi(u);
    }
    ushort2 ao; ao.x = f2bf(outv.x); ao.y = f2bf(outv.y);
    *(ushort2*)&aggb[(size_t)r * 128 + 2 * lane] = ao;
}

// ---------------------------------------------------------------------------
// gemm2 standalone (K=256, A = [featb|aggb]) + bn2 coefs in last block.
__global__ __launch_bounds__(256) void gemm_bn2(
    const unsigned short* __restrict__ A_lo,
    const unsigned short* __restrict__ A_hi,
    const unsigned short* __restrict__ Bb,
    const float* __restrict__ bias,
    float* __restrict__ Y,
    double* __restrict__ sum, double* __restrict__ sumsq, int N,
    int* __restrict__ done, int GB,
    const float* __restrict__ gamma, const float* __restrict__ beta,
    float* __restrict__ a, float* __restrict__ b, double invN)
{
    gemm_body<256>(blockIdx.x, A_lo, A_hi, Bb, bias, Y, sum, sumsq, N,
                   done, GB, gamma, beta, a, b, invN);
}

// ---------------------------------------------------------------------------
// bn2 affine (precomputed coefs) + row L2 normalize.
__global__ __launch_bounds__(256) void finalize(
    const float* __restrict__ Y2,
    const float* __restrict__ a, const float* __restrict__ b,
    float* __restrict__ out, int N)
{
    __shared__ float sa[128], sb[128];
    const int t = threadIdx.x;
    if (t < 128) { sa[t] = a[t]; sb[t] = b[t]; }
    __syncthreads();
    const int row  = (int)((blockIdx.x * 256u + t) >> 6);
    const int lane = t & 63;
    if (row >= N) return;
    const size_t base = (size_t)row * 128;
    float v0 = fmaf(sa[lane],      Y2[base + lane],      sb[lane]);
    float v1 = fmaf(sa[lane + 64], Y2[base + lane + 64], sb[lane + 64]);
    float ss = fmaf(v0, v0, v1 * v1);
#pragma unroll
    for (int o = 32; o; o >>= 1) ss += __shfl_xor(ss, o, 64);
    float nrm = sqrtf(ss);
    float inv = (nrm == 0.f) ? 1.f : 1.f / nrm;
    out[base + lane]      = v0 * inv;
    out[base + lane + 64] = v1 * inv;
}

// ---------------------------------------------------------------------------
extern "C" void kernel_launch(void* const* d_in, const int* in_sizes, int n_in,
                              void* d_out, int out_size, void* d_ws, size_t ws_size,
                              hipStream_t stream)
{
    const float* feat   = (const float*)d_in[0];
    const float* w      = (const float*)d_in[1];
    const float* Q_w    = (const float*)d_in[2];
    const float* Q_b    = (const float*)d_in[3];
    const float* W_w    = (const float*)d_in[4];
    const float* W_b    = (const float*)d_in[5];
    const float* gamma2 = (const float*)d_in[6];
    const float* beta2  = (const float*)d_in[7];
    const int*   src    = (const int*)d_in[8];
    const int*   dst    = (const int*)d_in[9];

    const int N = in_sizes[0] / 128;   // 50000
    const int E = in_sizes[1];         // 800000

    // workspace layout
    float*          y1    = (float*)d_ws;                            // N*128 f32 (y1 then y2)
    unsigned short* featb = (unsigned short*)(y1 + (size_t)N * 128); // N*128 bf16
    unsigned short* aggb  = featb + (size_t)N * 128;                 // N*128 bf16
    unsigned short* h_bf  = aggb + (size_t)N * 128;                  // N*128 bf16
    int4*  tmp    = (int4*)(h_bf + (size_t)N * 128);                 // E (16B aligned)
    int2*  epack  = (int2*)(tmp + E);                                // E
    int*   offs   = (int*)(epack + E);                               // N+1
    int*   coffs  = offs + (N + 1);                                  // 129
    int*   gcur   = coffs + 129;                                     // 128
    float* coefs  = (float*)(gcur + 128);                            // 512
    float* a1 = coefs, *b1 = coefs + 128, *a2 = coefs + 256, *b2 = coefs + 384;
    uintptr_t qp = ((uintptr_t)(coefs + 512) + 15) & ~(uintptr_t)15;
    unsigned short* Qwb = (unsigned short*)qp;                       // 128*128 bf16
    unsigned short* Wwb = Qwb + 128 * 128;                           // 128*256 bf16
    uintptr_t sp = ((uintptr_t)(Wwb + 128 * 256) + 15) & ~(uintptr_t)15;
    double* stats = (double*)sp;                                     // 4*NSLOT*128 <- zeroed
    double* sum1   = stats;
    double* sumsq1 = stats + NSLOT * 128;
    double* sum2   = stats + 2 * NSLOT * 128;
    double* sumsq2 = stats + 3 * NSLOT * 128;
    int*   ccnt   = (int*)(stats + 4 * NSLOT * 128);                 // 128 <- zeroed
    int*   done   = ccnt + 128;                                      // 4   <- zeroed

    hipMemsetAsync(stats, 0,
                   4 * NSLOT * 128 * sizeof(double) + 132 * sizeof(int),
                   stream);

    const double invN = 1.0 / (double)N;
    const int GB = (N + 63) / 64;               // gemm blocks (782)
    const int NB = (N + 511) >> 9;              // coarse buckets (98)
    const int CB = (N * 128 / 4 + 255) / 256;   // feat cast blocks
    const int HB = (E + 2047) / 2048;           // histogram/bin blocks
    const int AB = (N * 128 / 4 + 255) / 256;   // apply_bn blocks
    const int QB = 16;                          // Q_w cast blocks
    const int WB = 32;                          // W_w cast blocks

    k_pre<<<CB + HB + QB + WB, 256, 0, stream>>>(
        feat, featb, N * 128, dst, ccnt, E, CB, HB,
        Q_w, Qwb, W_w, Wwb, done, coffs, gcur, offs, N);

    // fatB: bin || gemm1 (+bn1 coefs in last gemm block)
    k_bin_gemm<<<HB + GB, 256, 0, stream>>>(
        src, dst, w, gcur, tmp, E, HB,
        featb, Qwb, Q_b, y1, sum1, sumsq1, N,
        done + 1, GB, gamma2, beta2, a1, b1, invN);

    // fatC: refine || apply_bn
    k_refine_apply<<<NB + AB, 256, 0, stream>>>(
        tmp, coffs, offs, epack, N, NB,
        y1, a1, b1, h_bf, N * 128);

    gather_agg<<<(N * 64 + 255) / 256, 256, 0, stream>>>(h_bf, offs, epack, aggb, N);

    gemm_bn2<<<GB, 256, 0, stream>>>(
        featb, aggb, Wwb, W_b, y1 /*=y2*/, sum2, sumsq2, N,
        done + 2, GB, gamma2, beta2, a2, b2, invN);

    finalize<<<(N * 64 + 255) / 256, 256, 0, stream>>>(
        y1, a2, b2, (float*)d_out, N);
}

// Round 3
// 234.430 us; speedup vs baseline: 1.7112x; 1.6539x over previous
//
#include <hip/hip_runtime.h>
#include <stdint.h>

// PinConv pipeline, round 13:
//  - REVERT all dispatch-fusion fences (rounds 11/12 regression: every block's
//    __threadfence() on gfx950 = agent-scope release = L2 writeback across
//    8 non-coherent XCDs -> continuous L2 flush, all pipes idle). Back to
//    round-10's 9-dispatch structure; tiny k_coffs/bn_coef kernels are far
//    cheaper than per-block fences.
//  - KEEP: Q_w/W_w pre-converted to bf16 once in k_pre, so GEMM B-staging is
//    a pure uint4 copy (no f2bf VALU in the K-loop of 1564 GEMM blocks).

#define BN_EPS 1e-5f
#define NSLOT 32

typedef __attribute__((ext_vector_type(8))) short bf16x8;
typedef __attribute__((ext_vector_type(4))) float f32x4;

static __device__ __forceinline__ unsigned short f2bf(float f) {
    uint32_t u = __builtin_bit_cast(uint32_t, f);
    u += 0x7fffu + ((u >> 16) & 1u);          // round-to-nearest-even
    return (unsigned short)(u >> 16);
}
static __device__ __forceinline__ float bf_lo(uint32_t u) {
    return __builtin_bit_cast(float, u << 16);
}
static __device__ __forceinline__ float bf_hi(uint32_t u) {
    return __builtin_bit_cast(float, u & 0xffff0000u);
}

static __device__ __forceinline__ void cast_blk(
    const float* __restrict__ src, unsigned short* __restrict__ dst,
    int n, int blk)
{
    int i = (blk * 256 + threadIdx.x) * 4;
    if (i + 3 < n) {
        float4 v = *(const float4*)(src + i);
        ushort4 o;
        o.x = f2bf(v.x); o.y = f2bf(v.y); o.z = f2bf(v.z); o.w = f2bf(v.w);
        *(ushort4*)(dst + i) = o;
    } else {
        for (int j = i; j < n; ++j) dst[j] = f2bf(src[j]);
    }
}

// ---------------------------------------------------------------------------
// Fused: blocks [0,CB) cast feat; [CB,CB+HB) coarse-histogram dst into
// 512-wide buckets; [CB+HB,..) cast Q_w / W_w to bf16. No fences.
__global__ __launch_bounds__(256) void k_pre(
    const float* __restrict__ feat, unsigned short* __restrict__ featb, int nf,
    const int* __restrict__ dst, int* __restrict__ ccnt, int E, int CB, int HB,
    const float* __restrict__ Qw, unsigned short* __restrict__ Qwb,
    const float* __restrict__ Ww, unsigned short* __restrict__ Wwb)
{
    int b = (int)blockIdx.x;
    if (b < CB) { cast_blk(feat, featb, nf, b); return; }
    b -= CB;
    if (b >= HB) {
        b -= HB;
        if (b < 16) cast_blk(Qw, Qwb, 128 * 128, b);
        else        cast_blk(Ww, Wwb, 128 * 256, b - 16);
        return;
    }
    __shared__ int hcnt[128];
    const int tid = threadIdx.x;
    if (tid < 128) hcnt[tid] = 0;
    __syncthreads();
    const int base_e = b * 2048;
#pragma unroll
    for (int j = 0; j < 8; ++j) {
        int e = base_e + j * 256 + tid;
        if (e < E) atomicAdd(&hcnt[dst[e] >> 9], 1);
    }
    __syncthreads();
    if (tid < 128 && hcnt[tid] > 0) atomicAdd(&ccnt[tid], hcnt[tid]);
}

// ---------------------------------------------------------------------------
// Single block: exclusive scan of 128 bucket counts -> coffs[129], gcur,
// and offs[N] = E.
__global__ __launch_bounds__(128) void k_coffs(
    const int* __restrict__ ccnt, int* __restrict__ coffs,
    int* __restrict__ gcur, int* __restrict__ offs, int N, int E)
{
    __shared__ int w0sum;
    const int t = threadIdx.x;
    const int lane = t & 63, wv = t >> 6;
    int v = ccnt[t];
    int incl = v;
#pragma unroll
    for (int o = 1; o < 64; o <<= 1) {
        int u = __shfl_up(incl, o, 64);
        if (lane >= o) incl += u;
    }
    if (wv == 0 && lane == 63) w0sum = incl;
    __syncthreads();
    int excl = incl - v + (wv ? w0sum : 0);
    coffs[t] = excl;
    gcur[t]  = excl;
    if (t == 127) { coffs[128] = excl + v; offs[N] = E; }
}

// ---------------------------------------------------------------------------
// GEMM body (LDS-staged): Y = relu(A @ B^T + bias); A rows bf16 from
// A_lo/A_hi (K split at 128). B bf16 [128][K] pre-converted -> staging is a
// pure uint4 copy. Col sum/sumsq -> striped fp64 slots. No fences.
template<int K>
static __device__ __forceinline__ void gemm_body(
    int bid,
    const unsigned short* __restrict__ A_lo,
    const unsigned short* __restrict__ A_hi,
    const unsigned short* __restrict__ Bb,
    const float* __restrict__ bias,
    float* __restrict__ Y,
    double* __restrict__ sum, double* __restrict__ sumsq, int N)
{
    constexpr int SA = 72;
    __shared__ unsigned short As[64 * SA];
    __shared__ unsigned short Bs[128 * SA];
    __shared__ float bsum_s[128], bsq_s[128];

    const int tid  = threadIdx.x;
    const int lane = tid & 63;
    const int wv   = tid >> 6;
    const int wr   = wv >> 1;
    const int wc   = wv & 1;
    const int m15  = lane & 15;
    const int quad = lane >> 4;
    const int r0   = bid * 64;

    if (tid < 128) { bsum_s[tid] = 0.f; bsq_s[tid] = 0.f; }

    f32x4 acc[2][4];
#pragma unroll
    for (int rt = 0; rt < 2; ++rt)
#pragma unroll
        for (int ct = 0; ct < 4; ++ct)
            acc[rt][ct] = (f32x4){0.f, 0.f, 0.f, 0.f};

    for (int kc = 0; kc < K; kc += 64) {
        const unsigned short* Ap = (kc < 128) ? A_lo : A_hi;
        const int koff = kc & 127;
        // A tile: 64 rows x 64 bf16 -> 2 x 256 x 16B
#pragma unroll
        for (int i = 0; i < 2; ++i) {
            int idx = i * 256 + tid;
            int row = idx >> 3, seg = idx & 7;
            int gr  = r0 + row; if (gr >= N) gr = N - 1;
            uint4 v = *(const uint4*)(Ap + (size_t)gr * 128 + koff + seg * 8);
            *(uint4*)(As + row * SA + seg * 8) = v;
        }
        // B tile: 128 rows x 64 bf16 -> 4 x 256 x 16B (pure copy)
#pragma unroll
        for (int i = 0; i < 4; ++i) {
            int idx = i * 256 + tid;
            int row = idx >> 3, seg = idx & 7;
            uint4 v = *(const uint4*)(Bb + (size_t)row * K + kc + seg * 8);
            *(uint4*)(Bs + row * SA + seg * 8) = v;
        }
        __syncthreads();

#pragma unroll
        for (int ks = 0; ks < 64; ks += 32) {
            bf16x8 af[2], bfr[4];
#pragma unroll
            for (int rt = 0; rt < 2; ++rt)
                af[rt] = *(const bf16x8*)(As + (wr * 32 + rt * 16 + m15) * SA + ks + quad * 8);
#pragma unroll
            for (int ct = 0; ct < 4; ++ct)
                bfr[ct] = *(const bf16x8*)(Bs + (wc * 64 + ct * 16 + m15) * SA + ks + quad * 8);
#pragma unroll
            for (int rt = 0; rt < 2; ++rt)
#pragma unroll
                for (int ct = 0; ct < 4; ++ct)
                    acc[rt][ct] = __builtin_amdgcn_mfma_f32_16x16x32_bf16(
                        af[rt], bfr[ct], acc[rt][ct], 0, 0, 0);
        }
        __syncthreads();
    }

#pragma unroll
    for (int ct = 0; ct < 4; ++ct) {
        int col = wc * 64 + ct * 16 + m15;
        float bz = bias[col];
        float s = 0.f, q = 0.f;
#pragma unroll
        for (int rt = 0; rt < 2; ++rt) {
#pragma unroll
            for (int reg = 0; reg < 4; ++reg) {
                int row = r0 + wr * 32 + rt * 16 + quad * 4 + reg;
                float vv = fmaxf(acc[rt][ct][reg] + bz, 0.f);
                if (row < N) {
                    Y[(size_t)row * 128 + col] = vv;
                } else {
                    vv = 0.f;
                }
                s += vv; q = fmaf(vv, vv, q);
            }
        }
        s += __shfl_xor(s, 16, 64); s += __shfl_xor(s, 32, 64);
        q += __shfl_xor(q, 16, 64); q += __shfl_xor(q, 32, 64);
        if (quad == 0) {
            atomicAdd(&bsum_s[col], s);
            atomicAdd(&bsq_s[col], q);
        }
    }
    __syncthreads();
    if (tid < 128) {
        const int slot = (bid & (NSLOT - 1)) * 128;
        atomicAdd(&sum[slot + tid],   (double)bsum_s[tid]);
        atomicAdd(&sumsq[slot + tid], (double)bsq_s[tid]);
    }
}

// ---------------------------------------------------------------------------
// Single block: reduce 32 slots -> bn affine coefs a[128], b[128].
__global__ __launch_bounds__(128) void bn_coef(
    const double* __restrict__ sum, const double* __restrict__ sumsq,
    const float* __restrict__ gamma, const float* __restrict__ beta,
    float* __restrict__ a, float* __restrict__ b, double invN)
{
    const int t = threadIdx.x;  // 128
    double ms = 0.0, qs = 0.0;
#pragma unroll
    for (int s = 0; s < NSLOT; ++s) {
        ms += sum[s * 128 + t];
        qs += sumsq[s * 128 + t];
    }
    float mean = (float)(ms * invN);
    float var  = (float)(qs * invN) - mean * mean;
    float sc = rsqrtf(var + BN_EPS) * gamma[t];
    a[t] = sc;
    b[t] = fmaf(-mean, sc, beta[t]);
}

// ---------------------------------------------------------------------------
// bin body: bin edges into coarse buckets of 512 dsts (int4 records).
static __device__ __forceinline__ void bin_body(
    int bid,
    const int* __restrict__ src, const int* __restrict__ dst,
    const float* __restrict__ w, int* __restrict__ gcur,
    int4* __restrict__ tmp, int E)
{
    __shared__ int hcnt[128];
    __shared__ int hbase[128];
    const int tid = threadIdx.x;
    if (tid < 128) hcnt[tid] = 0;
    __syncthreads();

    int d8[8], s8[8], slot8[8];
    float w8[8];
#pragma unroll
    for (int j = 0; j < 8; ++j) {
        int e = bid * 2048 + j * 256 + tid;
        if (e < E) {
            d8[j] = dst[e]; s8[j] = src[e]; w8[j] = w[e];
            slot8[j] = atomicAdd(&hcnt[d8[j] >> 9], 1);
        } else d8[j] = -1;
    }
    __syncthreads();
    if (tid < 128 && hcnt[tid] > 0)
        hbase[tid] = atomicAdd(&gcur[tid], hcnt[tid]);
    __syncthreads();
#pragma unroll
    for (int j = 0; j < 8; ++j) {
        if (d8[j] >= 0) {
            int pos = hbase[d8[j] >> 9] + slot8[j];
            tmp[pos] = make_int4(s8[j], __float_as_int(w8[j]), d8[j], 0);
        }
    }
}

// fatB: blocks [0,HB) bin edges; blocks [HB,HB+GB) run gemm1.
__global__ __launch_bounds__(256) void k_bin_gemm(
    const int* __restrict__ src, const int* __restrict__ dst,
    const float* __restrict__ w, int* __restrict__ gcur,
    int4* __restrict__ tmp, int E, int HB,
    const unsigned short* __restrict__ featb,
    const unsigned short* __restrict__ Qwb, const float* __restrict__ Qb,
    float* __restrict__ y1,
    double* __restrict__ sum, double* __restrict__ sumsq, int N)
{
    if ((int)blockIdx.x < HB)
        bin_body(blockIdx.x, src, dst, w, gcur, tmp, E);
    else
        gemm_body<128>(blockIdx.x - HB, featb, featb, Qwb, Qb, y1, sum, sumsq, N);
}

// ---------------------------------------------------------------------------
// refine body: per bucket — count per-dst in LDS, scan (+coffs base), write
// offs slice, scatter records to epack in exact dst order.
static __device__ __forceinline__ void refine_body(
    int b,
    const int4* __restrict__ tmp, const int* __restrict__ coffs,
    int* __restrict__ offs, int2* __restrict__ epack, int N)
{
    __shared__ int hist[512];
    __shared__ int wpre[4];
    const int d0   = b << 9;
    const int dlim = min(512, N - d0);
    const int tid  = threadIdx.x;
    const int lane = tid & 63, wv = tid >> 6;
    const int start = coffs[b];
    const int end   = coffs[b + 1];

    hist[tid] = 0; hist[tid + 256] = 0;
    __syncthreads();

    for (int p = start + tid; p < end; p += 256)
        atomicAdd(&hist[tmp[p].z - d0], 1);
    __syncthreads();

    int v0 = hist[2 * tid], v1 = hist[2 * tid + 1];
    int s = v0 + v1;
    int incl = s;
#pragma unroll
    for (int o = 1; o < 64; o <<= 1) {
        int t = __shfl_up(incl, o, 64);
        if (lane >= o) incl += t;
    }
    if (lane == 63) wpre[wv] = incl;
    __syncthreads();
    if (tid == 0) {
        int r = 0;
#pragma unroll
        for (int i = 0; i < 4; ++i) { int t = wpre[i]; wpre[i] = r; r += t; }
    }
    __syncthreads();
    int e0 = start + wpre[wv] + incl - s;
    if (2 * tid < dlim)     offs[d0 + 2 * tid]     = e0;
    if (2 * tid + 1 < dlim) offs[d0 + 2 * tid + 1] = e0 + v0;
    hist[2 * tid]     = e0;
    hist[2 * tid + 1] = e0 + v0;
    __syncthreads();

    for (int p = start + tid; p < end; p += 256) {
        int4 rec = tmp[p];
        int pos = atomicAdd(&hist[rec.z - d0], 1);
        epack[pos] = make_int2(rec.x, rec.y);
    }
}

// fatC: blocks [0,NB) refine buckets; blocks [NB,..) apply bn -> h bf16.
__global__ __launch_bounds__(256) void k_refine_apply(
    const int4* __restrict__ tmp, const int* __restrict__ coffs,
    int* __restrict__ offs, int2* __restrict__ epack, int N, int NB,
    const float* __restrict__ y,
    const float* __restrict__ a, const float* __restrict__ b,
    unsigned short* __restrict__ h, int n)
{
    if ((int)blockIdx.x < NB) {
        refine_body(blockIdx.x, tmp, coffs, offs, epack, N);
    } else {
        int i = ((blockIdx.x - NB) * 256 + threadIdx.x) * 4;
        if (i >= n) return;
        int c = i & 127;
        float4 v  = *(const float4*)(y + i);
        float4 av = *(const float4*)(a + c);
        float4 bv = *(const float4*)(b + c);
        ushort4 o;
        o.x = f2bf(fmaf(av.x, v.x, bv.x));
        o.y = f2bf(fmaf(av.y, v.y, bv.y));
        o.z = f2bf(fmaf(av.z, v.z, bv.z));
        o.w = f2bf(fmaf(av.w, v.w, bv.w));
        *(ushort4*)(h + i) = o;
    }
}

// ---------------------------------------------------------------------------
// One wave per dst row; h bf16 (bn applied). Writes agg only (bf16).
__global__ __launch_bounds__(256) void gather_agg(
    const unsigned short* __restrict__ h,
    const int* __restrict__ offs, const int2* __restrict__ epack,
    unsigned short* __restrict__ aggb, int N)
{
    const int r    = (int)((blockIdx.x * 256u + threadIdx.x) >> 6);
    const int lane = threadIdx.x & 63;
    if (r >= N) return;
    int p = offs[r];
    const int end = offs[r + 1];
    float nx = 0.f, ny = 0.f, den = 0.f;
    for (; p + 3 < end; p += 4) {
        int2 e0 = epack[p],     e1 = epack[p + 1];
        int2 e2 = epack[p + 2], e3 = epack[p + 3];
        uint32_t u0 = *(const uint32_t*)(h + (size_t)e0.x * 128 + 2 * lane);
        uint32_t u1 = *(const uint32_t*)(h + (size_t)e1.x * 128 + 2 * lane);
        uint32_t u2 = *(const uint32_t*)(h + (size_t)e2.x * 128 + 2 * lane);
        uint32_t u3 = *(const uint32_t*)(h + (size_t)e3.x * 128 + 2 * lane);
        float w0 = __int_as_float(e0.y), w1 = __int_as_float(e1.y);
        float w2 = __int_as_float(e2.y), w3 = __int_as_float(e3.y);
        nx = fmaf(w0, bf_lo(u0), nx); ny = fmaf(w0, bf_hi(u0), ny);
        nx = fmaf(w1, bf_lo(u1), nx); ny = fmaf(w1, bf_hi(u1), ny);
        nx = fmaf(w2, bf_lo(u2), nx); ny = fmaf(w2, bf_hi(u2), ny);
        nx = fmaf(w3, bf_lo(u3), nx); ny = fmaf(w3, bf_hi(u3), ny);
        den += (w0 + w1) + (w2 + w3);
    }
    for (; p < end; ++p) {
        int2 e0 = epack[p];
        float w0 = __int_as_float(e0.y);
        uint32_t u0 = *(const uint32_t*)(h + (size_t)e0.x * 128 + 2 * lane);
        nx = fmaf(w0, bf_lo(u0), nx); ny = fmaf(w0, bf_hi(u0), ny);
        den += w0;
    }
    float2 outv;
    if (den != 0.f) {
        float inv = 1.f / den;
        outv.x = nx * inv; outv.y = ny * inv;
    } else {
        uint32_t u = *(const uint32_t*)(h + (size_t)r * 128 + 2 * lane);
        outv.x = bf_lo(u); outv.y = bf_hi(u);
    }
    ushort2 ao; ao.x = f2bf(outv.x); ao.y = f2bf(outv.y);
    *(ushort2*)&aggb[(size_t)r * 128 + 2 * lane] = ao;
}

// ---------------------------------------------------------------------------
// gemm2 standalone (K=256, A = [featb|aggb]).
__global__ __launch_bounds__(256) void gemm_bn2(
    const unsigned short* __restrict__ A_lo,
    const unsigned short* __restrict__ A_hi,
    const unsigned short* __restrict__ Bb,
    const float* __restrict__ bias,
    float* __restrict__ Y,
    double* __restrict__ sum, double* __restrict__ sumsq, int N)
{
    gemm_body<256>(blockIdx.x, A_lo, A_hi, Bb, bias, Y, sum, sumsq, N);
}

// ---------------------------------------------------------------------------
// bn2 affine (precomputed coefs) + row L2 normalize.
__global__ __launch_bounds__(256) void finalize(
    const float* __restrict__ Y2,
    const float* __restrict__ a, const float* __restrict__ b,
    float* __restrict__ out, int N)
{
    __shared__ float sa[128], sb[128];
    const int t = threadIdx.x;
    if (t < 128) { sa[t] = a[t]; sb[t] = b[t]; }
    __syncthreads();
    const int row  = (int)((blockIdx.x * 256u + t) >> 6);
    const int lane = t & 63;
    if (row >= N) return;
    const size_t base = (size_t)row * 128;
    float v0 = fmaf(sa[lane],      Y2[base + lane],      sb[lane]);
    float v1 = fmaf(sa[lane + 64], Y2[base + lane + 64], sb[lane + 64]);
    float ss = fmaf(v0, v0, v1 * v1);
#pragma unroll
    for (int o = 32; o; o >>= 1) ss += __shfl_xor(ss, o, 64);
    float nrm = sqrtf(ss);
    float inv = (nrm == 0.f) ? 1.f : 1.f / nrm;
    out[base + lane]      = v0 * inv;
    out[base + lane + 64] = v1 * inv;
}

// ---------------------------------------------------------------------------
extern "C" void kernel_launch(void* const* d_in, const int* in_sizes, int n_in,
                              void* d_out, int out_size, void* d_ws, size_t ws_size,
                              hipStream_t stream)
{
    const float* feat   = (const float*)d_in[0];
    const float* w      = (const float*)d_in[1];
    const float* Q_w    = (const float*)d_in[2];
    const float* Q_b    = (const float*)d_in[3];
    const float* W_w    = (const float*)d_in[4];
    const float* W_b    = (const float*)d_in[5];
    const float* gamma2 = (const float*)d_in[6];
    const float* beta2  = (const float*)d_in[7];
    const int*   src    = (const int*)d_in[8];
    const int*   dst    = (const int*)d_in[9];

    const int N = in_sizes[0] / 128;   // 50000
    const int E = in_sizes[1];         // 800000

    // workspace layout
    float*          y1    = (float*)d_ws;                            // N*128 f32 (y1 then y2)
    unsigned short* featb = (unsigned short*)(y1 + (size_t)N * 128); // N*128 bf16
    unsigned short* aggb  = featb + (size_t)N * 128;                 // N*128 bf16
    unsigned short* h_bf  = aggb + (size_t)N * 128;                  // N*128 bf16
    int4*  tmp    = (int4*)(h_bf + (size_t)N * 128);                 // E (16B aligned)
    int2*  epack  = (int2*)(tmp + E);                                // E
    int*   offs   = (int*)(epack + E);                               // N+1
    int*   coffs  = offs + (N + 1);                                  // 129
    int*   gcur   = coffs + 129;                                     // 128
    float* coefs  = (float*)(gcur + 128);                            // 512
    float* a1 = coefs, *b1 = coefs + 128, *a2 = coefs + 256, *b2 = coefs + 384;
    uintptr_t qp = ((uintptr_t)(coefs + 512) + 15) & ~(uintptr_t)15;
    unsigned short* Qwb = (unsigned short*)qp;                       // 128*128 bf16
    unsigned short* Wwb = Qwb + 128 * 128;                           // 128*256 bf16
    uintptr_t sp = ((uintptr_t)(Wwb + 128 * 256) + 15) & ~(uintptr_t)15;
    double* stats = (double*)sp;                                     // 4*NSLOT*128 <- zeroed
    double* sum1   = stats;
    double* sumsq1 = stats + NSLOT * 128;
    double* sum2   = stats + 2 * NSLOT * 128;
    double* sumsq2 = stats + 3 * NSLOT * 128;
    int*   ccnt   = (int*)(stats + 4 * NSLOT * 128);                 // 128 <- zeroed

    hipMemsetAsync(stats, 0,
                   4 * NSLOT * 128 * sizeof(double) + 128 * sizeof(int),
                   stream);

    const double invN = 1.0 / (double)N;
    const int GB = (N + 63) / 64;               // gemm blocks (782)
    const int NB = (N + 511) >> 9;              // coarse buckets (98)
    const int CB = (N * 128 / 4 + 255) / 256;   // feat cast blocks
    const int HB = (E + 2047) / 2048;           // histogram/bin blocks
    const int AB = (N * 128 / 4 + 255) / 256;   // apply_bn blocks
    const int QB = 16;                          // Q_w cast blocks
    const int WB = 32;                          // W_w cast blocks

    k_pre<<<CB + HB + QB + WB, 256, 0, stream>>>(
        feat, featb, N * 128, dst, ccnt, E, CB, HB,
        Q_w, Qwb, W_w, Wwb);
    k_coffs<<<1, 128, 0, stream>>>(ccnt, coffs, gcur, offs, N, E);

    // fatB: bin || gemm1
    k_bin_gemm<<<HB + GB, 256, 0, stream>>>(
        src, dst, w, gcur, tmp, E, HB,
        featb, Qwb, Q_b, y1, sum1, sumsq1, N);
    bn_coef<<<1, 128, 0, stream>>>(sum1, sumsq1, gamma2, beta2, a1, b1, invN);

    // fatC: refine || apply_bn
    k_refine_apply<<<NB + AB, 256, 0, stream>>>(
        tmp, coffs, offs, epack, N, NB,
        y1, a1, b1, h_bf, N * 128);

    gather_agg<<<(N * 64 + 255) / 256, 256, 0, stream>>>(h_bf, offs, epack, aggb, N);

    gemm_bn2<<<GB, 256, 0, stream>>>(
        featb, aggb, Wwb, W_b, y1 /*=y2*/, sum2, sumsq2, N);
    bn_coef<<<1, 128, 0, stream>>>(sum2, sumsq2, gamma2, beta2, a2, b2, invN);
    finalize<<<(N * 64 + 255) / 256, 256, 0, stream>>>(
        y1, a2, b2, (float*)d_out, N);
}

// Round 4
// 227.663 us; speedup vs baseline: 1.7621x; 1.0297x over previous
//
#include <hip/hip_runtime.h>
#include <stdint.h>

// PinConv pipeline, round 14:
//  - bn1 APPLY commuted through the weighted mean: gather reads raw relu
//    output y1b (bf16, written directly by gemm1) and applies the bn affine
//    (a1,b1) once per output row: mean_w(a*y+b) = a*mean_w(y)+b, and the
//    den==0 fallback h[r]=a*y[r]+b uses the same map. Deletes the bn-apply
//    pass (25.6MB R + 12.8MB W) and halves gemm1's output write.
//  - gather_agg restructured 2-edges-per-wave: 32-lane halves, uint2 (8B)
//    loads = 4 columns/lane; halves per-edge VALU + load-instr count;
//    halves combined with one __shfl_xor(...,32).
//  - refine fused with bn_coef1 into one dispatch (block 0 = bn_coef).
//  - 8 dispatches, no device-scope fences (round-12 lesson).

#define BN_EPS 1e-5f
#define NSLOT 32

typedef __attribute__((ext_vector_type(8))) short bf16x8;
typedef __attribute__((ext_vector_type(4))) float f32x4;

static __device__ __forceinline__ unsigned short f2bf(float f) {
    uint32_t u = __builtin_bit_cast(uint32_t, f);
    u += 0x7fffu + ((u >> 16) & 1u);          // round-to-nearest-even
    return (unsigned short)(u >> 16);
}
static __device__ __forceinline__ float bf_lo(uint32_t u) {
    return __builtin_bit_cast(float, u << 16);
}
static __device__ __forceinline__ float bf_hi(uint32_t u) {
    return __builtin_bit_cast(float, u & 0xffff0000u);
}

static __device__ __forceinline__ void cast_blk(
    const float* __restrict__ src, unsigned short* __restrict__ dst,
    int n, int blk)
{
    int i = (blk * 256 + threadIdx.x) * 4;
    if (i + 3 < n) {
        float4 v = *(const float4*)(src + i);
        ushort4 o;
        o.x = f2bf(v.x); o.y = f2bf(v.y); o.z = f2bf(v.z); o.w = f2bf(v.w);
        *(ushort4*)(dst + i) = o;
    } else {
        for (int j = i; j < n; ++j) dst[j] = f2bf(src[j]);
    }
}

// ---------------------------------------------------------------------------
// Fused: blocks [0,CB) cast feat; [CB,CB+HB) coarse-histogram dst into
// 512-wide buckets; [CB+HB,..) cast Q_w / W_w to bf16. No fences.
__global__ __launch_bounds__(256) void k_pre(
    const float* __restrict__ feat, unsigned short* __restrict__ featb, int nf,
    const int* __restrict__ dst, int* __restrict__ ccnt, int E, int CB, int HB,
    const float* __restrict__ Qw, unsigned short* __restrict__ Qwb,
    const float* __restrict__ Ww, unsigned short* __restrict__ Wwb)
{
    int b = (int)blockIdx.x;
    if (b < CB) { cast_blk(feat, featb, nf, b); return; }
    b -= CB;
    if (b >= HB) {
        b -= HB;
        if (b < 16) cast_blk(Qw, Qwb, 128 * 128, b);
        else        cast_blk(Ww, Wwb, 128 * 256, b - 16);
        return;
    }
    __shared__ int hcnt[128];
    const int tid = threadIdx.x;
    if (tid < 128) hcnt[tid] = 0;
    __syncthreads();
    const int base_e = b * 2048;
#pragma unroll
    for (int j = 0; j < 8; ++j) {
        int e = base_e + j * 256 + tid;
        if (e < E) atomicAdd(&hcnt[dst[e] >> 9], 1);
    }
    __syncthreads();
    if (tid < 128 && hcnt[tid] > 0) atomicAdd(&ccnt[tid], hcnt[tid]);
}

// ---------------------------------------------------------------------------
// Single block: exclusive scan of 128 bucket counts -> coffs[129], gcur,
// and offs[N] = E.
__global__ __launch_bounds__(128) void k_coffs(
    const int* __restrict__ ccnt, int* __restrict__ coffs,
    int* __restrict__ gcur, int* __restrict__ offs, int N, int E)
{
    __shared__ int w0sum;
    const int t = threadIdx.x;
    const int lane = t & 63, wv = t >> 6;
    int v = ccnt[t];
    int incl = v;
#pragma unroll
    for (int o = 1; o < 64; o <<= 1) {
        int u = __shfl_up(incl, o, 64);
        if (lane >= o) incl += u;
    }
    if (wv == 0 && lane == 63) w0sum = incl;
    __syncthreads();
    int excl = incl - v + (wv ? w0sum : 0);
    coffs[t] = excl;
    gcur[t]  = excl;
    if (t == 127) { coffs[128] = excl + v; offs[N] = E; }
}

// ---------------------------------------------------------------------------
// GEMM body (LDS-staged): Y = relu(A @ B^T + bias); A rows bf16 from
// A_lo/A_hi (K split at 128). B bf16 [128][K] pre-converted -> staging is a
// pure uint4 copy. Output f32 or bf16 (template). Col sum/sumsq on the f32
// relu values -> striped fp64 slots. No fences.
template<int K, bool OUT_BF16>
static __device__ __forceinline__ void gemm_body(
    int bid,
    const unsigned short* __restrict__ A_lo,
    const unsigned short* __restrict__ A_hi,
    const unsigned short* __restrict__ Bb,
    const float* __restrict__ bias,
    void* __restrict__ Yv,
    double* __restrict__ sum, double* __restrict__ sumsq, int N)
{
    constexpr int SA = 72;
    __shared__ unsigned short As[64 * SA];
    __shared__ unsigned short Bs[128 * SA];
    __shared__ float bsum_s[128], bsq_s[128];

    const int tid  = threadIdx.x;
    const int lane = tid & 63;
    const int wv   = tid >> 6;
    const int wr   = wv >> 1;
    const int wc   = wv & 1;
    const int m15  = lane & 15;
    const int quad = lane >> 4;
    const int r0   = bid * 64;

    if (tid < 128) { bsum_s[tid] = 0.f; bsq_s[tid] = 0.f; }

    f32x4 acc[2][4];
#pragma unroll
    for (int rt = 0; rt < 2; ++rt)
#pragma unroll
        for (int ct = 0; ct < 4; ++ct)
            acc[rt][ct] = (f32x4){0.f, 0.f, 0.f, 0.f};

    for (int kc = 0; kc < K; kc += 64) {
        const unsigned short* Ap = (kc < 128) ? A_lo : A_hi;
        const int koff = kc & 127;
        // A tile: 64 rows x 64 bf16 -> 2 x 256 x 16B
#pragma unroll
        for (int i = 0; i < 2; ++i) {
            int idx = i * 256 + tid;
            int row = idx >> 3, seg = idx & 7;
            int gr  = r0 + row; if (gr >= N) gr = N - 1;
            uint4 v = *(const uint4*)(Ap + (size_t)gr * 128 + koff + seg * 8);
            *(uint4*)(As + row * SA + seg * 8) = v;
        }
        // B tile: 128 rows x 64 bf16 -> 4 x 256 x 16B (pure copy)
#pragma unroll
        for (int i = 0; i < 4; ++i) {
            int idx = i * 256 + tid;
            int row = idx >> 3, seg = idx & 7;
            uint4 v = *(const uint4*)(Bb + (size_t)row * K + kc + seg * 8);
            *(uint4*)(Bs + row * SA + seg * 8) = v;
        }
        __syncthreads();

#pragma unroll
        for (int ks = 0; ks < 64; ks += 32) {
            bf16x8 af[2], bfr[4];
#pragma unroll
            for (int rt = 0; rt < 2; ++rt)
                af[rt] = *(const bf16x8*)(As + (wr * 32 + rt * 16 + m15) * SA + ks + quad * 8);
#pragma unroll
            for (int ct = 0; ct < 4; ++ct)
                bfr[ct] = *(const bf16x8*)(Bs + (wc * 64 + ct * 16 + m15) * SA + ks + quad * 8);
#pragma unroll
            for (int rt = 0; rt < 2; ++rt)
#pragma unroll
                for (int ct = 0; ct < 4; ++ct)
                    acc[rt][ct] = __builtin_amdgcn_mfma_f32_16x16x32_bf16(
                        af[rt], bfr[ct], acc[rt][ct], 0, 0, 0);
        }
        __syncthreads();
    }

#pragma unroll
    for (int ct = 0; ct < 4; ++ct) {
        int col = wc * 64 + ct * 16 + m15;
        float bz = bias[col];
        float s = 0.f, q = 0.f;
#pragma unroll
        for (int rt = 0; rt < 2; ++rt) {
#pragma unroll
            for (int reg = 0; reg < 4; ++reg) {
                int row = r0 + wr * 32 + rt * 16 + quad * 4 + reg;
                float vv = fmaxf(acc[rt][ct][reg] + bz, 0.f);
                if (row < N) {
                    if constexpr (OUT_BF16)
                        ((unsigned short*)Yv)[(size_t)row * 128 + col] = f2bf(vv);
                    else
                        ((float*)Yv)[(size_t)row * 128 + col] = vv;
                } else {
                    vv = 0.f;
                }
                s += vv; q = fmaf(vv, vv, q);
            }
        }
        s += __shfl_xor(s, 16, 64); s += __shfl_xor(s, 32, 64);
        q += __shfl_xor(q, 16, 64); q += __shfl_xor(q, 32, 64);
        if (quad == 0) {
            atomicAdd(&bsum_s[col], s);
            atomicAdd(&bsq_s[col], q);
        }
    }
    __syncthreads();
    if (tid < 128) {
        const int slot = (bid & (NSLOT - 1)) * 128;
        atomicAdd(&sum[slot + tid],   (double)bsum_s[tid]);
        atomicAdd(&sumsq[slot + tid], (double)bsq_s[tid]);
    }
}

// ---------------------------------------------------------------------------
// bn coef body: reduce 32 slots -> bn affine coefs a[128], b[128]. t in [0,128).
static __device__ __forceinline__ void bn_coef_body(
    int t, const double* __restrict__ sum, const double* __restrict__ sumsq,
    const float* __restrict__ gamma, const float* __restrict__ beta,
    float* __restrict__ a, float* __restrict__ b, double invN)
{
    double ms = 0.0, qs = 0.0;
#pragma unroll
    for (int s = 0; s < NSLOT; ++s) {
        ms += sum[s * 128 + t];
        qs += sumsq[s * 128 + t];
    }
    float mean = (float)(ms * invN);
    float var  = (float)(qs * invN) - mean * mean;
    float sc = rsqrtf(var + BN_EPS) * gamma[t];
    a[t] = sc;
    b[t] = fmaf(-mean, sc, beta[t]);
}

__global__ __launch_bounds__(128) void bn_coef(
    const double* __restrict__ sum, const double* __restrict__ sumsq,
    const float* __restrict__ gamma, const float* __restrict__ beta,
    float* __restrict__ a, float* __restrict__ b, double invN)
{
    bn_coef_body(threadIdx.x, sum, sumsq, gamma, beta, a, b, invN);
}

// ---------------------------------------------------------------------------
// bin body: bin edges into coarse buckets of 512 dsts (int4 records).
static __device__ __forceinline__ void bin_body(
    int bid,
    const int* __restrict__ src, const int* __restrict__ dst,
    const float* __restrict__ w, int* __restrict__ gcur,
    int4* __restrict__ tmp, int E)
{
    __shared__ int hcnt[128];
    __shared__ int hbase[128];
    const int tid = threadIdx.x;
    if (tid < 128) hcnt[tid] = 0;
    __syncthreads();

    int d8[8], s8[8], slot8[8];
    float w8[8];
#pragma unroll
    for (int j = 0; j < 8; ++j) {
        int e = bid * 2048 + j * 256 + tid;
        if (e < E) {
            d8[j] = dst[e]; s8[j] = src[e]; w8[j] = w[e];
            slot8[j] = atomicAdd(&hcnt[d8[j] >> 9], 1);
        } else d8[j] = -1;
    }
    __syncthreads();
    if (tid < 128 && hcnt[tid] > 0)
        hbase[tid] = atomicAdd(&gcur[tid], hcnt[tid]);
    __syncthreads();
#pragma unroll
    for (int j = 0; j < 8; ++j) {
        if (d8[j] >= 0) {
            int pos = hbase[d8[j] >> 9] + slot8[j];
            tmp[pos] = make_int4(s8[j], __float_as_int(w8[j]), d8[j], 0);
        }
    }
}

// fatB: blocks [0,HB) bin edges; blocks [HB,HB+GB) run gemm1 -> y1b bf16.
__global__ __launch_bounds__(256) void k_bin_gemm(
    const int* __restrict__ src, const int* __restrict__ dst,
    const float* __restrict__ w, int* __restrict__ gcur,
    int4* __restrict__ tmp, int E, int HB,
    const unsigned short* __restrict__ featb,
    const unsigned short* __restrict__ Qwb, const float* __restrict__ Qb,
    unsigned short* __restrict__ y1b,
    double* __restrict__ sum, double* __restrict__ sumsq, int N)
{
    if ((int)blockIdx.x < HB)
        bin_body(blockIdx.x, src, dst, w, gcur, tmp, E);
    else
        gemm_body<128, true>(blockIdx.x - HB, featb, featb, Qwb, Qb, y1b,
                             sum, sumsq, N);
}

// ---------------------------------------------------------------------------
// refine body: per bucket — count per-dst in LDS, scan (+coffs base), write
// offs slice, scatter records to epack in exact dst order.
static __device__ __forceinline__ void refine_body(
    int b,
    const int4* __restrict__ tmp, const int* __restrict__ coffs,
    int* __restrict__ offs, int2* __restrict__ epack, int N)
{
    __shared__ int hist[512];
    __shared__ int wpre[4];
    const int d0   = b << 9;
    const int dlim = min(512, N - d0);
    const int tid  = threadIdx.x;
    const int lane = tid & 63, wv = tid >> 6;
    const int start = coffs[b];
    const int end   = coffs[b + 1];

    hist[tid] = 0; hist[tid + 256] = 0;
    __syncthreads();

    for (int p = start + tid; p < end; p += 256)
        atomicAdd(&hist[tmp[p].z - d0], 1);
    __syncthreads();

    int v0 = hist[2 * tid], v1 = hist[2 * tid + 1];
    int s = v0 + v1;
    int incl = s;
#pragma unroll
    for (int o = 1; o < 64; o <<= 1) {
        int t = __shfl_up(incl, o, 64);
        if (lane >= o) incl += t;
    }
    if (lane == 63) wpre[wv] = incl;
    __syncthreads();
    if (tid == 0) {
        int r = 0;
#pragma unroll
        for (int i = 0; i < 4; ++i) { int t = wpre[i]; wpre[i] = r; r += t; }
    }
    __syncthreads();
    int e0 = start + wpre[wv] + incl - s;
    if (2 * tid < dlim)     offs[d0 + 2 * tid]     = e0;
    if (2 * tid + 1 < dlim) offs[d0 + 2 * tid + 1] = e0 + v0;
    hist[2 * tid]     = e0;
    hist[2 * tid + 1] = e0 + v0;
    __syncthreads();

    for (int p = start + tid; p < end; p += 256) {
        int4 rec = tmp[p];
        int pos = atomicAdd(&hist[rec.z - d0], 1);
        epack[pos] = make_int2(rec.x, rec.y);
    }
}

// fat: block 0 = bn_coef1 reduce; blocks [1,NB] = refine buckets.
__global__ __launch_bounds__(256) void k_bnref(
    const double* __restrict__ sum, const double* __restrict__ sumsq,
    const float* __restrict__ gamma, const float* __restrict__ beta,
    float* __restrict__ a, float* __restrict__ b, double invN,
    const int4* __restrict__ tmp, const int* __restrict__ coffs,
    int* __restrict__ offs, int2* __restrict__ epack, int N)
{
    if (blockIdx.x == 0) {
        if (threadIdx.x < 128)
            bn_coef_body(threadIdx.x, sum, sumsq, gamma, beta, a, b, invN);
        return;
    }
    refine_body((int)blockIdx.x - 1, tmp, coffs, offs, epack, N);
}

// ---------------------------------------------------------------------------
// One wave per dst row, 2 edges in flight (32-lane halves, 4 cols/lane).
// Reads raw relu y1b; applies bn affine (a,b) to the weighted mean (or to
// the own row when den==0). Writes agg bf16.
__global__ __launch_bounds__(256) void gather_agg(
    const unsigned short* __restrict__ y1b,
    const int* __restrict__ offs, const int2* __restrict__ epack,
    const float* __restrict__ a, const float* __restrict__ b,
    unsigned short* __restrict__ aggb, int N)
{
    const int r    = (int)((blockIdx.x * 256u + threadIdx.x) >> 6);
    const int lane = threadIdx.x & 63;
    const int li   = lane & 31;     // owns columns 4*li .. 4*li+3
    const int hf   = lane >> 5;     // 0: even edge of pair, 1: odd
    if (r >= N) return;
    int p = offs[r];
    const int end = offs[r + 1];
    float ac0 = 0.f, ac1 = 0.f, ac2 = 0.f, ac3 = 0.f, den = 0.f;
    for (; p + 3 < end; p += 4) {
        int2 ea = epack[p + hf];
        int2 eb = epack[p + 2 + hf];
        uint2 ua = *(const uint2*)(y1b + (size_t)ea.x * 128 + 4 * li);
        uint2 ub = *(const uint2*)(y1b + (size_t)eb.x * 128 + 4 * li);
        float wa = __int_as_float(ea.y), wb = __int_as_float(eb.y);
        ac0 = fmaf(wa, bf_lo(ua.x), ac0); ac1 = fmaf(wa, bf_hi(ua.x), ac1);
        ac2 = fmaf(wa, bf_lo(ua.y), ac2); ac3 = fmaf(wa, bf_hi(ua.y), ac3);
        ac0 = fmaf(wb, bf_lo(ub.x), ac0); ac1 = fmaf(wb, bf_hi(ub.x), ac1);
        ac2 = fmaf(wb, bf_lo(ub.y), ac2); ac3 = fmaf(wb, bf_hi(ub.y), ac3);
        den += wa + wb;
    }
    for (; p + 1 < end; p += 2) {
        int2 ea = epack[p + hf];
        uint2 ua = *(const uint2*)(y1b + (size_t)ea.x * 128 + 4 * li);
        float wa = __int_as_float(ea.y);
        ac0 = fmaf(wa, bf_lo(ua.x), ac0); ac1 = fmaf(wa, bf_hi(ua.x), ac1);
        ac2 = fmaf(wa, bf_lo(ua.y), ac2); ac3 = fmaf(wa, bf_hi(ua.y), ac3);
        den += wa;
    }
    if (p < end && hf == 0) {   // odd tail edge: half 0 only
        int2 ea = epack[p];
        uint2 ua = *(const uint2*)(y1b + (size_t)ea.x * 128 + 4 * li);
        float wa = __int_as_float(ea.y);
        ac0 = fmaf(wa, bf_lo(ua.x), ac0); ac1 = fmaf(wa, bf_hi(ua.x), ac1);
        ac2 = fmaf(wa, bf_lo(ua.y), ac2); ac3 = fmaf(wa, bf_hi(ua.y), ac3);
        den += wa;
    }
    ac0 += __shfl_xor(ac0, 32, 64);
    ac1 += __shfl_xor(ac1, 32, 64);
    ac2 += __shfl_xor(ac2, 32, 64);
    ac3 += __shfl_xor(ac3, 32, 64);
    den += __shfl_xor(den, 32, 64);
    if (hf) return;
    const int c = 4 * li;
    float4 av = *(const float4*)(a + c);
    float4 bv = *(const float4*)(b + c);
    float m0, m1, m2, m3;
    if (den != 0.f) {
        float inv = 1.f / den;
        m0 = ac0 * inv; m1 = ac1 * inv; m2 = ac2 * inv; m3 = ac3 * inv;
    } else {
        uint2 u = *(const uint2*)(y1b + (size_t)r * 128 + c);
        m0 = bf_lo(u.x); m1 = bf_hi(u.x); m2 = bf_lo(u.y); m3 = bf_hi(u.y);
    }
    ushort4 o;
    o.x = f2bf(fmaf(av.x, m0, bv.x));
    o.y = f2bf(fmaf(av.y, m1, bv.y));
    o.z = f2bf(fmaf(av.z, m2, bv.z));
    o.w = f2bf(fmaf(av.w, m3, bv.w));
    *(ushort4*)(aggb + (size_t)r * 128 + c) = o;
}

// ---------------------------------------------------------------------------
// gemm2 standalone (K=256, A = [featb|aggb]) -> y2 f32 + stats2.
__global__ __launch_bounds__(256) void gemm_bn2(
    const unsigned short* __restrict__ A_lo,
    const unsigned short* __restrict__ A_hi,
    const unsigned short* __restrict__ Bb,
    const float* __restrict__ bias,
    float* __restrict__ Y,
    double* __restrict__ sum, double* __restrict__ sumsq, int N)
{
    gemm_body<256, false>(blockIdx.x, A_lo, A_hi, Bb, bias, Y, sum, sumsq, N);
}

// ---------------------------------------------------------------------------
// bn2 affine (precomputed coefs) + row L2 normalize.
__global__ __launch_bounds__(256) void finalize(
    const float* __restrict__ Y2,
    const float* __restrict__ a, const float* __restrict__ b,
    float* __restrict__ out, int N)
{
    __shared__ float sa[128], sb[128];
    const int t = threadIdx.x;
    if (t < 128) { sa[t] = a[t]; sb[t] = b[t]; }
    __syncthreads();
    const int row  = (int)((blockIdx.x * 256u + t) >> 6);
    const int lane = t & 63;
    if (row >= N) return;
    const size_t base = (size_t)row * 128;
    float v0 = fmaf(sa[lane],      Y2[base + lane],      sb[lane]);
    float v1 = fmaf(sa[lane + 64], Y2[base + lane + 64], sb[lane + 64]);
    float ss = fmaf(v0, v0, v1 * v1);
#pragma unroll
    for (int o = 32; o; o >>= 1) ss += __shfl_xor(ss, o, 64);
    float nrm = sqrtf(ss);
    float inv = (nrm == 0.f) ? 1.f : 1.f / nrm;
    out[base + lane]      = v0 * inv;
    out[base + lane + 64] = v1 * inv;
}

// ---------------------------------------------------------------------------
extern "C" void kernel_launch(void* const* d_in, const int* in_sizes, int n_in,
                              void* d_out, int out_size, void* d_ws, size_t ws_size,
                              hipStream_t stream)
{
    const float* feat   = (const float*)d_in[0];
    const float* w      = (const float*)d_in[1];
    const float* Q_w    = (const float*)d_in[2];
    const float* Q_b    = (const float*)d_in[3];
    const float* W_w    = (const float*)d_in[4];
    const float* W_b    = (const float*)d_in[5];
    const float* gamma2 = (const float*)d_in[6];
    const float* beta2  = (const float*)d_in[7];
    const int*   src    = (const int*)d_in[8];
    const int*   dst    = (const int*)d_in[9];

    const int N = in_sizes[0] / 128;   // 50000
    const int E = in_sizes[1];         // 800000

    // workspace layout
    float*          y2    = (float*)d_ws;                            // N*128 f32
    unsigned short* featb = (unsigned short*)(y2 + (size_t)N * 128); // N*128 bf16
    unsigned short* aggb  = featb + (size_t)N * 128;                 // N*128 bf16
    unsigned short* y1b   = aggb + (size_t)N * 128;                  // N*128 bf16
    int4*  tmp    = (int4*)(y1b + (size_t)N * 128);                  // E (16B aligned)
    int2*  epack  = (int2*)(tmp + E);                                // E
    int*   offs   = (int*)(epack + E);                               // N+1
    int*   coffs  = offs + (N + 1);                                  // 129
    int*   gcur   = coffs + 129;                                     // 128
    float* coefs  = (float*)(gcur + 128);                            // 512
    float* a1 = coefs, *b1 = coefs + 128, *a2 = coefs + 256, *b2 = coefs + 384;
    uintptr_t qp = ((uintptr_t)(coefs + 512) + 15) & ~(uintptr_t)15;
    unsigned short* Qwb = (unsigned short*)qp;                       // 128*128 bf16
    unsigned short* Wwb = Qwb + 128 * 128;                           // 128*256 bf16
    uintptr_t sp = ((uintptr_t)(Wwb + 128 * 256) + 15) & ~(uintptr_t)15;
    double* stats = (double*)sp;                                     // 4*NSLOT*128 <- zeroed
    double* sum1   = stats;
    double* sumsq1 = stats + NSLOT * 128;
    double* sum2   = stats + 2 * NSLOT * 128;
    double* sumsq2 = stats + 3 * NSLOT * 128;
    int*   ccnt   = (int*)(stats + 4 * NSLOT * 128);                 // 128 <- zeroed

    hipMemsetAsync(stats, 0,
                   4 * NSLOT * 128 * sizeof(double) + 128 * sizeof(int),
                   stream);

    const double invN = 1.0 / (double)N;
    const int GB = (N + 63) / 64;               // gemm blocks (782)
    const int NB = (N + 511) >> 9;              // coarse buckets (98)
    const int CB = (N * 128 / 4 + 255) / 256;   // feat cast blocks
    const int HB = (E + 2047) / 2048;           // histogram/bin blocks
    const int QB = 16;                          // Q_w cast blocks
    const int WB = 32;                          // W_w cast blocks

    k_pre<<<CB + HB + QB + WB, 256, 0, stream>>>(
        feat, featb, N * 128, dst, ccnt, E, CB, HB,
        Q_w, Qwb, W_w, Wwb);
    k_coffs<<<1, 128, 0, stream>>>(ccnt, coffs, gcur, offs, N, E);

    // fatB: bin || gemm1 -> y1b bf16 + stats1
    k_bin_gemm<<<HB + GB, 256, 0, stream>>>(
        src, dst, w, gcur, tmp, E, HB,
        featb, Qwb, Q_b, y1b, sum1, sumsq1, N);

    // fat: bn_coef1 (block 0) || refine (blocks 1..NB)
    k_bnref<<<NB + 1, 256, 0, stream>>>(
        sum1, sumsq1, gamma2, beta2, a1, b1, invN,
        tmp, coffs, offs, epack, N);

    gather_agg<<<(N * 64 + 255) / 256, 256, 0, stream>>>(
        y1b, offs, epack, a1, b1, aggb, N);

    gemm_bn2<<<GB, 256, 0, stream>>>(
        featb, aggb, Wwb, W_b, y2, sum2, sumsq2, N);
    bn_coef<<<1, 128, 0, stream>>>(sum2, sumsq2, gamma2, beta2, a2, b2, invN);
    finalize<<<(N * 64 + 255) / 256, 256, 0, stream>>>(
        y2, a2, b2, (float*)d_out, N);
}